// Round 1
// baseline (727.134 us; speedup 1.0000x reference)
//
#include <hip/hip_runtime.h>
#include <hip/hip_bf16.h>
#include <math.h>

typedef __attribute__((ext_vector_type(8))) short short8;
typedef __attribute__((ext_vector_type(4))) float f32x4;
typedef __attribute__((ext_vector_type(4))) unsigned short ushort4v;

#define MIX 0.5f
#define INJ_LAM 0.8f

__device__ inline float bf2f(unsigned short s){
  union{unsigned u; float f;} v; v.u=((unsigned)s)<<16; return v.f;
}
__device__ inline unsigned short f2bf(float f){
  __hip_bfloat16 h=__float2bfloat16(f);
  return *reinterpret_cast<unsigned short*>(&h);
}

__global__ void k_zero32(unsigned* __restrict__ p, int n){
  int i=blockIdx.x*blockDim.x+threadIdx.x;
  if(i<n) p[i]=0u;
}

__global__ void k_count(const int* __restrict__ dst, unsigned* __restrict__ cnt, int E){
  int e=blockIdx.x*blockDim.x+threadIdx.x;
  if(e<E) atomicAdd(&cnt[dst[e]],1u);
}

__global__ void k_dinv(const unsigned* __restrict__ cnt, float* __restrict__ dinv, int N){
  int i=blockIdx.x*blockDim.x+threadIdx.x;
  if(i<N) dinv[i]=rsqrtf((float)(cnt[i]+1u));   // +1 self-loop; deg>=1 always
}

// ---- scan over per-node counts -> CSR offsets (1024 counts per block) ----
__global__ void k_scan_a(const unsigned* __restrict__ cnt, unsigned* __restrict__ bsum, int N){
  __shared__ unsigned sh[256];
  int t=threadIdx.x, b=blockIdx.x;
  int base=b*1024+t*4;
  unsigned ts=0;
  #pragma unroll
  for(int j=0;j<4;j++){ int i=base+j; if(i<N) ts+=cnt[i]; }
  sh[t]=ts; __syncthreads();
  for(int off=128;off>0;off>>=1){ if(t<off) sh[t]+=sh[t+off]; __syncthreads(); }
  if(t==0) bsum[b]=sh[0];
}

__global__ void k_scan_b(const unsigned* __restrict__ bsum, unsigned* __restrict__ bo, int NB){
  if(threadIdx.x==0 && blockIdx.x==0){
    unsigned run=0;
    for(int i=0;i<NB;i++){ bo[i]=run; run+=bsum[i]; }
  }
}

__global__ void k_scan_c(const unsigned* __restrict__ cnt, const unsigned* __restrict__ bo,
                         unsigned* __restrict__ offs, unsigned* __restrict__ cursor, int N){
  __shared__ unsigned sh[256];
  int t=threadIdx.x, b=blockIdx.x;
  int base=b*1024+t*4;
  unsigned c[4]; unsigned ts=0;
  #pragma unroll
  for(int j=0;j<4;j++){ int i=base+j; c[j]=(i<N)?cnt[i]:0u; ts+=c[j]; }
  sh[t]=ts; __syncthreads();
  for(int off=1;off<256;off<<=1){
    unsigned v=(t>=off)?sh[t-off]:0u; __syncthreads();
    sh[t]+=v; __syncthreads();
  }
  unsigned run=sh[t]-ts+bo[b];
  #pragma unroll
  for(int j=0;j<4;j++){ int i=base+j; if(i<N){ offs[i]=run; cursor[i]=run; } run+=c[j]; }
}

__global__ void k_scatter(const int* __restrict__ src, const int* __restrict__ dst,
                          unsigned* __restrict__ cursor, int* __restrict__ csr, int E){
  int e=blockIdx.x*blockDim.x+threadIdx.x;
  if(e<E){ unsigned p=atomicAdd(&cursor[dst[e]],1u); csr[p]=src[e]; }
}

__global__ void k_cast(const float4* __restrict__ x, ushort4v* __restrict__ xb, int n4){
  int i=blockIdx.x*blockDim.x+threadIdx.x;
  if(i<n4){
    float4 v=x[i];
    ushort4v o; o[0]=f2bf(v.x); o[1]=f2bf(v.y); o[2]=f2bf(v.z); o[3]=f2bf(v.w);
    xb[i]=o;
  }
}

// weights: transpose+cast to bf16 [out][K] layout
__global__ void k_prepw(const float* __restrict__ W1,const float* __restrict__ Wl1,
                        const float* __restrict__ W2,const float* __restrict__ Wl2,
                        const float* __restrict__ Wm1,const float* __restrict__ Wm2,
                        unsigned short* __restrict__ Wt1, unsigned short* __restrict__ Wt2,
                        unsigned short* __restrict__ Wm1t, unsigned short* __restrict__ Wm2tp){
  int i=blockIdx.x*blockDim.x+threadIdx.x;
  if(i<256*128){
    int c=i>>7, k=i&127;
    float v1=(c<128)?W1[k*128+c]:Wl1[k*128+(c-128)];
    float v2=(c<128)?W2[k*128+c]:Wl2[k*128+(c-128)];
    Wt1[i]=f2bf(v1); Wt2[i]=f2bf(v2);
    if(c<128) Wm1t[i]=f2bf(Wm1[k*128+c]);
    if(c<16)  Wm2tp[i]=f2bf((c<10)?Wm2[k*10+c]:0.f);
  }
}

__global__ void k_mark(const int* __restrict__ idx, unsigned char* __restrict__ flag, int NI){
  int i=blockIdx.x*blockDim.x+threadIdx.x;
  if(i<NI) flag[idx[i]]=1;
}

// GEMM: X[N][128]bf16 @ Wt[256][128]^T -> cols 0..127: G = bf16(val*dinv[row]); cols 128..255: XL = bf16(val)
__launch_bounds__(256)
__global__ void k_gemm(const unsigned short* __restrict__ X, const unsigned short* __restrict__ Wt,
                       const float* __restrict__ dinv,
                       unsigned short* __restrict__ G, unsigned short* __restrict__ XL, int N){
  int wave=threadIdx.x>>6, lane=threadIdx.x&63;
  int l15=lane&15, l4=lane>>4;
  int node0=blockIdx.x*64+wave*16;
  if(node0>=N) return;
  int arow=node0+l15; if(arow>N-1) arow=N-1;
  short8 a[4];
  #pragma unroll
  for(int ks=0;ks<4;ks++)
    a[ks]=*reinterpret_cast<const short8*>(X+(size_t)arow*128+ks*32+l4*8);
  f32x4 acc[16];
  #pragma unroll
  for(int ct=0;ct<16;ct++) acc[ct]=(f32x4){0.f,0.f,0.f,0.f};
  #pragma unroll
  for(int ct=0;ct<16;ct++){
    int col=ct*16+l15;
    #pragma unroll
    for(int ks=0;ks<4;ks++){
      short8 bfr=*reinterpret_cast<const short8*>(Wt+(size_t)col*128+ks*32+l4*8);
      acc[ct]=__builtin_amdgcn_mfma_f32_16x16x32_bf16(a[ks],bfr,acc[ct],0,0,0);
    }
  }
  int rows[4]; float dv[4];
  #pragma unroll
  for(int r=0;r<4;r++){ rows[r]=node0+l4*4+r; dv[r]=(rows[r]<N)?dinv[rows[r]]:0.f; }
  #pragma unroll
  for(int ct=0;ct<16;ct++){
    int col=ct*16+l15;
    #pragma unroll
    for(int r=0;r<4;r++){
      if(rows[r]<N){
        float v=acc[ct][r];
        if(col<128) G [(size_t)rows[r]*128+col      ]=f2bf(v*dv[r]);
        else        XL[(size_t)rows[r]*128+(col-128)]=f2bf(v);
      }
    }
  }
}

// conv: per node (one wave): sum g[self] + g[neighbors], low=dinv*sum+b, out=0.5*low+0.5*xl (opt. relu)
template<bool RELU>
__launch_bounds__(256)
__global__ void k_conv(const unsigned short* __restrict__ G, const unsigned short* __restrict__ XL,
                       const float* __restrict__ bias, const float* __restrict__ dinv,
                       const int* __restrict__ csr, const unsigned* __restrict__ offs,
                       const unsigned* __restrict__ cnt,
                       unsigned short* __restrict__ H, int N){
  int node=blockIdx.x*4+(threadIdx.x>>6);
  if(node>=N) return;
  int lane=threadIdx.x&63;
  const unsigned* Gu=(const unsigned*)G;
  unsigned u0=Gu[(size_t)node*64+lane];           // self-loop term
  float ax=bf2f((unsigned short)(u0&0xffffu));
  float ay=bf2f((unsigned short)(u0>>16));
  unsigned start=offs[node], deg=cnt[node];
  for(unsigned j=0;j<deg;j++){
    int s=csr[start+j];
    unsigned u=Gu[(size_t)s*64+lane];
    ax+=bf2f((unsigned short)(u&0xffffu));
    ay+=bf2f((unsigned short)(u>>16));
  }
  float dv=dinv[node];
  float2 bb=*reinterpret_cast<const float2*>(bias+lane*2);
  unsigned ux=((const unsigned*)XL)[(size_t)node*64+lane];
  float r0=0.5f*(dv*ax+bb.x)+0.5f*bf2f((unsigned short)(ux&0xffffu));
  float r1=0.5f*(dv*ay+bb.y)+0.5f*bf2f((unsigned short)(ux>>16));
  if(RELU){ r0=fmaxf(r0,0.f); r1=fmaxf(r1,0.f); }
  unsigned o=((unsigned)f2bf(r1)<<16)|(unsigned)f2bf(r0);
  ((unsigned*)H)[(size_t)node*64+lane]=o;
}

// MLP head: relu(H2@Wm1+bm1)@Wm2+bm2 -> injection -> log_softmax -> out
__launch_bounds__(256)
__global__ void k_mlp(const unsigned short* __restrict__ H2,
                      const unsigned short* __restrict__ Wm1t,
                      const unsigned short* __restrict__ Wm2tp,
                      const float* __restrict__ bm1, const float* __restrict__ bm2,
                      const unsigned char* __restrict__ flag, const float* __restrict__ preds,
                      float* __restrict__ out, int N){
  __shared__ unsigned short zt[4][16][128];
  __shared__ float lt[4][16][16];
  int wave=threadIdx.x>>6, lane=threadIdx.x&63;
  int l15=lane&15, l4=lane>>4;
  int node0=blockIdx.x*64+wave*16;
  int arow=node0+l15; if(arow>N-1) arow=N-1; if(arow<0) arow=0;
  short8 a[4];
  #pragma unroll
  for(int ks=0;ks<4;ks++)
    a[ks]=*reinterpret_cast<const short8*>(H2+(size_t)arow*128+ks*32+l4*8);
  f32x4 acc[8];
  #pragma unroll
  for(int ct=0;ct<8;ct++) acc[ct]=(f32x4){0.f,0.f,0.f,0.f};
  #pragma unroll
  for(int ct=0;ct<8;ct++){
    int col=ct*16+l15;
    #pragma unroll
    for(int ks=0;ks<4;ks++){
      short8 bfr=*reinterpret_cast<const short8*>(Wm1t+(size_t)col*128+ks*32+l4*8);
      acc[ct]=__builtin_amdgcn_mfma_f32_16x16x32_bf16(a[ks],bfr,acc[ct],0,0,0);
    }
  }
  #pragma unroll
  for(int ct=0;ct<8;ct++){
    int col=ct*16+l15; float bm=bm1[col];
    #pragma unroll
    for(int r=0;r<4;r++)
      zt[wave][l4*4+r][col]=f2bf(fmaxf(acc[ct][r]+bm,0.f));
  }
  __syncthreads();
  short8 a2[4];
  #pragma unroll
  for(int ks=0;ks<4;ks++)
    a2[ks]=*reinterpret_cast<const short8*>(&zt[wave][l15][ks*32+l4*8]);
  f32x4 acc2=(f32x4){0.f,0.f,0.f,0.f};
  #pragma unroll
  for(int ks=0;ks<4;ks++){
    short8 bfr=*reinterpret_cast<const short8*>(Wm2tp+(size_t)l15*128+ks*32+l4*8);
    acc2=__builtin_amdgcn_mfma_f32_16x16x32_bf16(a2[ks],bfr,acc2,0,0,0);
  }
  #pragma unroll
  for(int r=0;r<4;r++) lt[wave][l4*4+r][l15]=acc2[r];
  __syncthreads();
  if(lane<16){
    int node=node0+lane;
    if(node<N){
      float v[10];
      #pragma unroll
      for(int c=0;c<10;c++) v[c]=lt[wave][lane][c]+bm2[c];
      if(flag[node]){
        #pragma unroll
        for(int c=0;c<10;c++) v[c]+=INJ_LAM*preds[(size_t)node*10+c];
      }
      float m=v[0];
      #pragma unroll
      for(int c=1;c<10;c++) m=fmaxf(m,v[c]);
      float s=0.f;
      #pragma unroll
      for(int c=0;c<10;c++) s+=expf(v[c]-m);
      float lse=m+logf(s);
      #pragma unroll
      for(int c=0;c<10;c++) out[(size_t)node*10+c]=v[c]-lse;
    }
  }
}

extern "C" void kernel_launch(void* const* d_in, const int* in_sizes, int n_in,
                              void* d_out, int out_size, void* d_ws, size_t ws_size,
                              hipStream_t stream){
  const float* x    =(const float*)d_in[0];
  const int*   ei   =(const int*)  d_in[1];
  const int*   inj  =(const int*)  d_in[2];
  const float* preds=(const float*)d_in[3];
  const float* W1 =(const float*)d_in[4];  const float* b1 =(const float*)d_in[5];
  const float* W2 =(const float*)d_in[6];  const float* b2 =(const float*)d_in[7];
  const float* Wl1=(const float*)d_in[8];  const float* Wl2=(const float*)d_in[9];
  const float* Wm1=(const float*)d_in[10]; const float* bm1=(const float*)d_in[11];
  const float* Wm2=(const float*)d_in[12]; const float* bm2=(const float*)d_in[13];
  float* out=(float*)d_out;

  const int N  = in_sizes[0]/128;
  const int E  = in_sizes[1]/2;
  const int NI = in_sizes[2];
  const int* srcp = ei;
  const int* dstp = ei+E;

  char* w=(char*)d_ws;
  auto carve=[&](size_t sz)->char*{ char* p=w; w+=(sz+255)&~(size_t)255; return p; };
  unsigned short* S0 =(unsigned short*)carve((size_t)N*128*2); // xb -> hb -> h2b
  unsigned short* S1 =(unsigned short*)carve((size_t)N*128*2); // g1b -> g2b
  unsigned short* S2 =(unsigned short*)carve((size_t)N*128*2); // xl1b -> xl2b
  unsigned short* Wt1=(unsigned short*)carve(256*128*2);
  unsigned short* Wt2=(unsigned short*)carve(256*128*2);
  unsigned short* Wm1t=(unsigned short*)carve(128*128*2);
  unsigned short* Wm2tp=(unsigned short*)carve(16*128*2);
  unsigned* cnt   =(unsigned*)carve((size_t)N*4);
  float*    dinv  =(float*)   carve((size_t)N*4);
  unsigned* offs  =(unsigned*)carve((size_t)N*4);
  unsigned* cursor=(unsigned*)carve((size_t)N*4);
  int*      csr   =(int*)     carve((size_t)E*4);
  unsigned char* flags=(unsigned char*)carve(((size_t)N+3)&~(size_t)3);
  const int NB=(N+1023)/1024;
  unsigned* bsum=(unsigned*)carve((size_t)NB*4);
  unsigned* bo  =(unsigned*)carve((size_t)NB*4);
  (void)ws_size; (void)n_in; (void)out_size;

  const int T=256;
  int nf4=(N+3)/4;
  hipLaunchKernelGGL(k_zero32, dim3((N+T-1)/T), dim3(T), 0, stream, cnt, N);
  hipLaunchKernelGGL(k_zero32, dim3((nf4+T-1)/T), dim3(T), 0, stream, (unsigned*)flags, nf4);
  hipLaunchKernelGGL(k_count, dim3((E+T-1)/T), dim3(T), 0, stream, dstp, cnt, E);
  hipLaunchKernelGGL(k_dinv, dim3((N+T-1)/T), dim3(T), 0, stream, cnt, dinv, N);
  hipLaunchKernelGGL(k_scan_a, dim3(NB), dim3(T), 0, stream, cnt, bsum, N);
  hipLaunchKernelGGL(k_scan_b, dim3(1), dim3(64), 0, stream, bsum, bo, NB);
  hipLaunchKernelGGL(k_scan_c, dim3(NB), dim3(T), 0, stream, cnt, bo, offs, cursor, N);
  hipLaunchKernelGGL(k_scatter, dim3((E+T-1)/T), dim3(T), 0, stream, srcp, dstp, cursor, csr, E);
  int n4=(N*128)/4;
  hipLaunchKernelGGL(k_cast, dim3((n4+T-1)/T), dim3(T), 0, stream, (const float4*)x, (ushort4v*)S0, n4);
  hipLaunchKernelGGL(k_prepw, dim3(128), dim3(T), 0, stream, W1,Wl1,W2,Wl2,Wm1,Wm2, Wt1,Wt2,Wm1t,Wm2tp);
  hipLaunchKernelGGL(k_mark, dim3((NI+T-1)/T), dim3(T), 0, stream, inj, flags, NI);

  dim3 gemmGrid((N+63)/64);
  hipLaunchKernelGGL(k_gemm, gemmGrid, dim3(T), 0, stream, S0, Wt1, dinv, S1, S2, N);
  hipLaunchKernelGGL(k_conv<true>,  dim3((N+3)/4), dim3(T), 0, stream, S1, S2, b1, dinv, csr, offs, cnt, S0, N);
  hipLaunchKernelGGL(k_gemm, gemmGrid, dim3(T), 0, stream, S0, Wt2, dinv, S1, S2, N);
  hipLaunchKernelGGL(k_conv<false>, dim3((N+3)/4), dim3(T), 0, stream, S1, S2, b2, dinv, csr, offs, cnt, S0, N);
  hipLaunchKernelGGL(k_mlp, gemmGrid, dim3(T), 0, stream, S0, Wm1t, Wm2tp, bm1, bm2, flags, preds, out, N);
}

// Round 2
// 541.102 us; speedup vs baseline: 1.3438x; 1.3438x over previous
//
#include <hip/hip_runtime.h>
#include <hip/hip_bf16.h>
#include <math.h>

typedef __attribute__((ext_vector_type(8))) short short8;
typedef __attribute__((ext_vector_type(4))) float f32x4;

#define INJ_LAM 0.8f

__device__ inline float bf2f(unsigned short s){
  union{unsigned u; float f;} v; v.u=((unsigned)s)<<16; return v.f;
}
__device__ inline unsigned short f2bf(float f){
  __hip_bfloat16 h=__float2bfloat16(f);
  return *reinterpret_cast<unsigned short*>(&h);
}
__device__ inline unsigned pack2(float lo, float hi){
  return ((unsigned)f2bf(hi)<<16)|(unsigned)f2bf(lo);
}

__global__ void k_count_mark(const int* __restrict__ dst, unsigned* __restrict__ cnt,
                             const int* __restrict__ inj, unsigned char* __restrict__ flag,
                             int E, int NI){
  int i=blockIdx.x*blockDim.x+threadIdx.x;
  if(i<E) atomicAdd(&cnt[dst[i]],1u);
  if(i<NI) flag[inj[i]]=1;
}

// ---- scan over per-node counts -> CSR offsets (1024 counts per block) ----
__global__ void k_scan_a(const unsigned* __restrict__ cnt, unsigned* __restrict__ bsum, int N){
  __shared__ unsigned sh[256];
  int t=threadIdx.x, b=blockIdx.x;
  int base=b*1024+t*4;
  unsigned ts=0;
  #pragma unroll
  for(int j=0;j<4;j++){ int i=base+j; if(i<N) ts+=cnt[i]; }
  sh[t]=ts; __syncthreads();
  for(int off=128;off>0;off>>=1){ if(t<off) sh[t]+=sh[t+off]; __syncthreads(); }
  if(t==0) bsum[b]=sh[0];
}

__global__ void k_scan_b(const unsigned* __restrict__ bsum, unsigned* __restrict__ bo, int NB){
  if(threadIdx.x==0 && blockIdx.x==0){
    unsigned run=0;
    for(int i=0;i<NB;i++){ bo[i]=run; run+=bsum[i]; }
  }
}

__global__ void k_scan_c(const unsigned* __restrict__ cnt, const unsigned* __restrict__ bo,
                         unsigned* __restrict__ offs, unsigned* __restrict__ cursor,
                         float* __restrict__ dinv, int N){
  __shared__ unsigned sh[256];
  int t=threadIdx.x, b=blockIdx.x;
  int base=b*1024+t*4;
  unsigned c[4]; unsigned ts=0;
  #pragma unroll
  for(int j=0;j<4;j++){ int i=base+j; c[j]=(i<N)?cnt[i]:0u; ts+=c[j]; }
  sh[t]=ts; __syncthreads();
  for(int off=1;off<256;off<<=1){
    unsigned v=(t>=off)?sh[t-off]:0u; __syncthreads();
    sh[t]+=v; __syncthreads();
  }
  unsigned run=sh[t]-ts+bo[b];
  #pragma unroll
  for(int j=0;j<4;j++){
    int i=base+j;
    if(i<N){ offs[i]=run; cursor[i]=run; dinv[i]=rsqrtf((float)(c[j]+1u)); }
    run+=c[j];
  }
}

__global__ void k_scatter(const int* __restrict__ src, const int* __restrict__ dst,
                          unsigned* __restrict__ cursor, int* __restrict__ csr, int E){
  int e=blockIdx.x*blockDim.x+threadIdx.x;
  if(e<E){ unsigned p=atomicAdd(&cursor[dst[e]],1u); csr[p]=src[e]; }
}

typedef __attribute__((ext_vector_type(4))) unsigned short ushort4v;
__global__ void k_cast(const float4* __restrict__ x, ushort4v* __restrict__ xb, int n4){
  int i=blockIdx.x*blockDim.x+threadIdx.x;
  if(i<n4){
    float4 v=x[i];
    ushort4v o; o[0]=f2bf(v.x); o[1]=f2bf(v.y); o[2]=f2bf(v.z); o[3]=f2bf(v.w);
    xb[i]=o;
  }
}

// weights: transpose+cast to bf16 [out][K] layout
__global__ void k_prepw(const float* __restrict__ W1,const float* __restrict__ Wl1,
                        const float* __restrict__ W2,const float* __restrict__ Wl2,
                        const float* __restrict__ Wm1,const float* __restrict__ Wm2,
                        unsigned short* __restrict__ Wt1, unsigned short* __restrict__ Wt2,
                        unsigned short* __restrict__ Wm1t, unsigned short* __restrict__ Wm2tp){
  int i=blockIdx.x*blockDim.x+threadIdx.x;
  if(i<256*128){
    int c=i>>7, k=i&127;
    float v1=(c<128)?W1[k*128+c]:Wl1[k*128+(c-128)];
    float v2=(c<128)?W2[k*128+c]:Wl2[k*128+(c-128)];
    Wt1[i]=f2bf(v1); Wt2[i]=f2bf(v2);
    if(c<128) Wm1t[i]=f2bf(Wm1[k*128+c]);
    if(c<16)  Wm2tp[i]=f2bf((c<10)?Wm2[k*10+c]:0.f);
  }
}

// GEMM: X[N][128]bf16 @ Wt[256][128]^T. Swapped-operand MFMA -> lane owns one
// node (l15) and 4 consecutive out-cols per acc reg -> packed 8B stores.
// cols 0..127: G = bf16(val*dinv[node]); cols 128..255: XL = bf16(val)
__launch_bounds__(256)
__global__ void k_gemm(const unsigned short* __restrict__ X, const unsigned short* __restrict__ Wt,
                       const float* __restrict__ dinv,
                       unsigned short* __restrict__ G, unsigned short* __restrict__ XL, int N){
  int wave=threadIdx.x>>6, lane=threadIdx.x&63;
  int l15=lane&15, l4=lane>>4;
  int node0=blockIdx.x*64+wave*16;
  if(node0>=N) return;
  int arow=node0+l15; if(arow>N-1) arow=N-1;
  short8 a[4];
  #pragma unroll
  for(int ks=0;ks<4;ks++)
    a[ks]=*reinterpret_cast<const short8*>(X+(size_t)arow*128+ks*32+l4*8);
  f32x4 acc[16];
  #pragma unroll
  for(int ct=0;ct<16;ct++) acc[ct]=(f32x4){0.f,0.f,0.f,0.f};
  #pragma unroll
  for(int ct=0;ct<16;ct++){
    #pragma unroll
    for(int ks=0;ks<4;ks++){
      short8 bfr=*reinterpret_cast<const short8*>(Wt+(size_t)(ct*16+l15)*128+ks*32+l4*8);
      acc[ct]=__builtin_amdgcn_mfma_f32_16x16x32_bf16(bfr,a[ks],acc[ct],0,0,0);
    }
  }
  int node=node0+l15;
  if(node<N){
    float dv=dinv[node];
    #pragma unroll
    for(int ct=0;ct<8;ct++){
      f32x4 v=acc[ct];
      uint2 p; p.x=pack2(v[0]*dv,v[1]*dv); p.y=pack2(v[2]*dv,v[3]*dv);
      *reinterpret_cast<uint2*>(G+(size_t)node*128+ct*16+l4*4)=p;
    }
    #pragma unroll
    for(int ct=8;ct<16;ct++){
      f32x4 v=acc[ct];
      uint2 p; p.x=pack2(v[0],v[1]); p.y=pack2(v[2],v[3]);
      *reinterpret_cast<uint2*>(XL+(size_t)node*128+(ct-8)*16+l4*4)=p;
    }
  }
}

#define ADDROW(acc,v) do{ \
  unsigned _x=(unsigned)(v).x,_y=(unsigned)(v).y,_z=(unsigned)(v).z,_w=(unsigned)(v).w; \
  acc[0]+=bf2f((unsigned short)(_x&0xffffu)); acc[1]+=bf2f((unsigned short)(_x>>16)); \
  acc[2]+=bf2f((unsigned short)(_y&0xffffu)); acc[3]+=bf2f((unsigned short)(_y>>16)); \
  acc[4]+=bf2f((unsigned short)(_z&0xffffu)); acc[5]+=bf2f((unsigned short)(_z>>16)); \
  acc[6]+=bf2f((unsigned short)(_w&0xffffu)); acc[7]+=bf2f((unsigned short)(_w>>16)); }while(0)

// conv: one node per wave; 4 neighbor rows in flight per iteration.
// lane = (g=lane>>4 neighbor slot, li=lane&15 16B chunk of the 256B row).
// cross-group shfl_xor reduce; low=dinv*sum+b; out=0.5*low+0.5*xl (opt relu)
template<bool RELU>
__launch_bounds__(256)
__global__ void k_conv(const unsigned short* __restrict__ G, const unsigned short* __restrict__ XL,
                       const float* __restrict__ bias, const float* __restrict__ dinv,
                       const int* __restrict__ csr, const unsigned* __restrict__ offs,
                       const unsigned* __restrict__ cnt,
                       unsigned short* __restrict__ H, int N){
  int node=blockIdx.x*4+(threadIdx.x>>6);
  if(node>=N) return;
  int lane=threadIdx.x&63;
  int g=lane>>4, li=lane&15;
  const int4* Gv=(const int4*)G;
  float acc[8];
  #pragma unroll
  for(int i=0;i<8;i++) acc[i]=0.f;
  if(g==0){
    int4 v=Gv[(size_t)node*16+li];       // self-loop term
    ADDROW(acc,v);
  }
  unsigned start=offs[node], deg=cnt[node];
  unsigned j=(unsigned)g;
  if(j<deg){
    int4 v=Gv[(size_t)csr[start+j]*16+li];
    j+=4;
    while(j<deg){
      int4 vn=Gv[(size_t)csr[start+j]*16+li];
      ADDROW(acc,v);
      v=vn; j+=4;
    }
    ADDROW(acc,v);
  }
  #pragma unroll
  for(int i=0;i<8;i++){
    acc[i]+=__shfl_xor(acc[i],16,64);
    acc[i]+=__shfl_xor(acc[i],32,64);
  }
  if(g==0){
    float dv=dinv[node];
    float4 b0=*reinterpret_cast<const float4*>(bias+li*8);
    float4 b1=*reinterpret_cast<const float4*>(bias+li*8+4);
    int4 xv=((const int4*)XL)[(size_t)node*16+li];
    float xl[8];
    { unsigned _x=(unsigned)xv.x,_y=(unsigned)xv.y,_z=(unsigned)xv.z,_w=(unsigned)xv.w;
      xl[0]=bf2f((unsigned short)(_x&0xffffu)); xl[1]=bf2f((unsigned short)(_x>>16));
      xl[2]=bf2f((unsigned short)(_y&0xffffu)); xl[3]=bf2f((unsigned short)(_y>>16));
      xl[4]=bf2f((unsigned short)(_z&0xffffu)); xl[5]=bf2f((unsigned short)(_z>>16));
      xl[6]=bf2f((unsigned short)(_w&0xffffu)); xl[7]=bf2f((unsigned short)(_w>>16)); }
    float bb[8]={b0.x,b0.y,b0.z,b0.w,b1.x,b1.y,b1.z,b1.w};
    float r[8];
    #pragma unroll
    for(int i=0;i<8;i++){
      r[i]=0.5f*(dv*acc[i]+bb[i])+0.5f*xl[i];
      if(RELU) r[i]=fmaxf(r[i],0.f);
    }
    int4 o;
    o.x=(int)pack2(r[0],r[1]); o.y=(int)pack2(r[2],r[3]);
    o.z=(int)pack2(r[4],r[5]); o.w=(int)pack2(r[6],r[7]);
    ((int4*)H)[(size_t)node*16+li]=o;
  }
}

// MLP head: relu(H2@Wm1+bm1)@Wm2+bm2 -> injection -> log_softmax -> out
__launch_bounds__(256)
__global__ void k_mlp(const unsigned short* __restrict__ H2,
                      const unsigned short* __restrict__ Wm1t,
                      const unsigned short* __restrict__ Wm2tp,
                      const float* __restrict__ bm1, const float* __restrict__ bm2,
                      const unsigned char* __restrict__ flag, const float* __restrict__ preds,
                      float* __restrict__ out, int N){
  __shared__ __align__(16) unsigned short zt[4][16][136];  // +8 pad: kills 16-way LDS conflict
  __shared__ __align__(16) float lt[4][16][16];
  int wave=threadIdx.x>>6, lane=threadIdx.x&63;
  int l15=lane&15, l4=lane>>4;
  int node0=blockIdx.x*64+wave*16;
  int arow=node0+l15; if(arow>N-1) arow=N-1; if(arow<0) arow=0;
  short8 a[4];
  #pragma unroll
  for(int ks=0;ks<4;ks++)
    a[ks]=*reinterpret_cast<const short8*>(H2+(size_t)arow*128+ks*32+l4*8);
  f32x4 acc[8];
  #pragma unroll
  for(int ct=0;ct<8;ct++) acc[ct]=(f32x4){0.f,0.f,0.f,0.f};
  #pragma unroll
  for(int ct=0;ct<8;ct++){
    #pragma unroll
    for(int ks=0;ks<4;ks++){
      short8 bfr=*reinterpret_cast<const short8*>(Wm1t+(size_t)(ct*16+l15)*128+ks*32+l4*8);
      acc[ct]=__builtin_amdgcn_mfma_f32_16x16x32_bf16(bfr,a[ks],acc[ct],0,0,0);
    }
  }
  // lane holds node=l15, hid cols ct*16+l4*4..+3 -> packed 8B LDS writes
  #pragma unroll
  for(int ct=0;ct<8;ct++){
    float4 bm=*reinterpret_cast<const float4*>(bm1+ct*16+l4*4);
    uint2 p;
    p.x=pack2(fmaxf(acc[ct][0]+bm.x,0.f),fmaxf(acc[ct][1]+bm.y,0.f));
    p.y=pack2(fmaxf(acc[ct][2]+bm.z,0.f),fmaxf(acc[ct][3]+bm.w,0.f));
    *reinterpret_cast<uint2*>(&zt[wave][l15][ct*16+l4*4])=p;
  }
  __syncthreads();
  short8 a2[4];
  #pragma unroll
  for(int ks=0;ks<4;ks++)
    a2[ks]=*reinterpret_cast<const short8*>(&zt[wave][l15][ks*32+l4*8]);
  f32x4 acc2=(f32x4){0.f,0.f,0.f,0.f};
  #pragma unroll
  for(int ks=0;ks<4;ks++){
    short8 bfr=*reinterpret_cast<const short8*>(Wm2tp+(size_t)l15*128+ks*32+l4*8);
    acc2=__builtin_amdgcn_mfma_f32_16x16x32_bf16(bfr,a2[ks],acc2,0,0,0);
  }
  // lane holds node=l15, classes l4*4..+3
  *reinterpret_cast<f32x4*>(&lt[wave][l15][l4*4])=acc2;
  __syncthreads();
  if(lane<16){
    int node=node0+lane;
    if(node<N){
      float v[10];
      #pragma unroll
      for(int c=0;c<10;c++) v[c]=lt[wave][lane][c]+bm2[c];
      if(flag[node]){
        #pragma unroll
        for(int c=0;c<10;c++) v[c]+=INJ_LAM*preds[(size_t)node*10+c];
      }
      float m=v[0];
      #pragma unroll
      for(int c=1;c<10;c++) m=fmaxf(m,v[c]);
      float s=0.f;
      #pragma unroll
      for(int c=0;c<10;c++) s+=expf(v[c]-m);
      float lse=m+logf(s);
      #pragma unroll
      for(int c=0;c<10;c++) out[(size_t)node*10+c]=v[c]-lse;
    }
  }
}

extern "C" void kernel_launch(void* const* d_in, const int* in_sizes, int n_in,
                              void* d_out, int out_size, void* d_ws, size_t ws_size,
                              hipStream_t stream){
  const float* x    =(const float*)d_in[0];
  const int*   ei   =(const int*)  d_in[1];
  const int*   inj  =(const int*)  d_in[2];
  const float* preds=(const float*)d_in[3];
  const float* W1 =(const float*)d_in[4];  const float* b1 =(const float*)d_in[5];
  const float* W2 =(const float*)d_in[6];  const float* b2 =(const float*)d_in[7];
  const float* Wl1=(const float*)d_in[8];  const float* Wl2=(const float*)d_in[9];
  const float* Wm1=(const float*)d_in[10]; const float* bm1=(const float*)d_in[11];
  const float* Wm2=(const float*)d_in[12]; const float* bm2=(const float*)d_in[13];
  float* out=(float*)d_out;

  const int N  = in_sizes[0]/128;
  const int E  = in_sizes[1]/2;
  const int NI = in_sizes[2];
  const int* srcp = ei;
  const int* dstp = ei+E;

  char* w=(char*)d_ws;
  auto carve=[&](size_t sz)->char*{ char* p=w; w+=(sz+255)&~(size_t)255; return p; };
  unsigned short* S0 =(unsigned short*)carve((size_t)N*128*2); // xb -> hb -> h2b
  unsigned short* S1 =(unsigned short*)carve((size_t)N*128*2); // g1b -> g2b
  unsigned short* S2 =(unsigned short*)carve((size_t)N*128*2); // xl1b -> xl2b
  unsigned short* Wt1=(unsigned short*)carve(256*128*2);
  unsigned short* Wt2=(unsigned short*)carve(256*128*2);
  unsigned short* Wm1t=(unsigned short*)carve(128*128*2);
  unsigned short* Wm2tp=(unsigned short*)carve(16*128*2);
  unsigned* cnt   =(unsigned*)carve((size_t)N*4);
  float*    dinv  =(float*)   carve((size_t)N*4);
  unsigned* offs  =(unsigned*)carve((size_t)N*4);
  unsigned* cursor=(unsigned*)carve((size_t)N*4);
  int*      csr   =(int*)     carve((size_t)E*4);
  unsigned char* flags=(unsigned char*)carve(((size_t)N+3)&~(size_t)3);
  const int NB=(N+1023)/1024;
  unsigned* bsum=(unsigned*)carve((size_t)NB*4);
  unsigned* bo  =(unsigned*)carve((size_t)NB*4);
  (void)ws_size; (void)n_in; (void)out_size;

  const int T=256;
  hipMemsetAsync(cnt, 0, (size_t)N*4, stream);
  hipMemsetAsync(flags, 0, (size_t)N, stream);
  hipLaunchKernelGGL(k_count_mark, dim3((E+T-1)/T), dim3(T), 0, stream, dstp, cnt, inj, flags, E, NI);
  hipLaunchKernelGGL(k_scan_a, dim3(NB), dim3(T), 0, stream, cnt, bsum, N);
  hipLaunchKernelGGL(k_scan_b, dim3(1), dim3(64), 0, stream, bsum, bo, NB);
  hipLaunchKernelGGL(k_scan_c, dim3(NB), dim3(T), 0, stream, cnt, bo, offs, cursor, dinv, N);
  hipLaunchKernelGGL(k_scatter, dim3((E+T-1)/T), dim3(T), 0, stream, srcp, dstp, cursor, csr, E);
  int n4=(N*128)/4;
  hipLaunchKernelGGL(k_cast, dim3((n4+T-1)/T), dim3(T), 0, stream, (const float4*)x, (ushort4v*)S0, n4);
  hipLaunchKernelGGL(k_prepw, dim3(128), dim3(T), 0, stream, W1,Wl1,W2,Wl2,Wm1,Wm2, Wt1,Wt2,Wm1t,Wm2tp);

  dim3 gemmGrid((N+63)/64);
  hipLaunchKernelGGL(k_gemm, gemmGrid, dim3(T), 0, stream, S0, Wt1, dinv, S1, S2, N);
  hipLaunchKernelGGL(k_conv<true>,  dim3((N+3)/4), dim3(T), 0, stream, S1, S2, b1, dinv, csr, offs, cnt, S0, N);
  hipLaunchKernelGGL(k_gemm, gemmGrid, dim3(T), 0, stream, S0, Wt2, dinv, S1, S2, N);
  hipLaunchKernelGGL(k_conv<false>, dim3((N+3)/4), dim3(T), 0, stream, S1, S2, b2, dinv, csr, offs, cnt, S0, N);
  hipLaunchKernelGGL(k_mlp, gemmGrid, dim3(T), 0, stream, S0, Wm1t, Wm2tp, bm1, bm2, flags, preds, out, N);
}

// Round 3
// 426.091 us; speedup vs baseline: 1.7065x; 1.2699x over previous
//
#include <hip/hip_runtime.h>
#include <hip/hip_bf16.h>
#include <math.h>

typedef __attribute__((ext_vector_type(8))) short short8;
typedef __attribute__((ext_vector_type(4))) float f32x4;

#define INJ_LAM 0.8f

__device__ inline float bf2f(unsigned short s){
  union{unsigned u; float f;} v; v.u=((unsigned)s)<<16; return v.f;
}
__device__ inline unsigned short f2bf(float f){
  __hip_bfloat16 h=__float2bfloat16(f);
  return *reinterpret_cast<unsigned short*>(&h);
}
__device__ inline unsigned pack2(float lo, float hi){
  return ((unsigned)f2bf(hi)<<16)|(unsigned)f2bf(lo);
}

// count degrees; atomic return value IS the edge's rank within its dst segment.
__global__ void k_count_mark(const int* __restrict__ dst, unsigned* __restrict__ cnt,
                             unsigned* __restrict__ rank,
                             const int* __restrict__ inj, unsigned char* __restrict__ flag,
                             int E, int NI){
  int i=blockIdx.x*blockDim.x+threadIdx.x;
  if(i<E) rank[i]=atomicAdd(&cnt[dst[i]],1u);
  if(i<NI) flag[inj[i]]=1;
}

// ---- scan over per-node counts -> CSR offsets (1024 counts per block) ----
__global__ void k_scan_a(const unsigned* __restrict__ cnt, unsigned* __restrict__ bsum, int N){
  __shared__ unsigned sh[256];
  int t=threadIdx.x, b=blockIdx.x;
  int base=b*1024+t*4;
  unsigned ts=0;
  #pragma unroll
  for(int j=0;j<4;j++){ int i=base+j; if(i<N) ts+=cnt[i]; }
  sh[t]=ts; __syncthreads();
  for(int off=128;off>0;off>>=1){ if(t<off) sh[t]+=sh[t+off]; __syncthreads(); }
  if(t==0) bsum[b]=sh[0];
}

__global__ void k_scan_b(const unsigned* __restrict__ bsum, unsigned* __restrict__ bo, int NB){
  if(threadIdx.x==0 && blockIdx.x==0){
    unsigned run=0;
    for(int i=0;i<NB;i++){ bo[i]=run; run+=bsum[i]; }
  }
}

__global__ void k_scan_c(const unsigned* __restrict__ cnt, const unsigned* __restrict__ bo,
                         unsigned* __restrict__ offs,
                         float* __restrict__ dinv, int N){
  __shared__ unsigned sh[256];
  int t=threadIdx.x, b=blockIdx.x;
  int base=b*1024+t*4;
  unsigned c[4]; unsigned ts=0;
  #pragma unroll
  for(int j=0;j<4;j++){ int i=base+j; c[j]=(i<N)?cnt[i]:0u; ts+=c[j]; }
  sh[t]=ts; __syncthreads();
  for(int off=1;off<256;off<<=1){
    unsigned v=(t>=off)?sh[t-off]:0u; __syncthreads();
    sh[t]+=v; __syncthreads();
  }
  unsigned run=sh[t]-ts+bo[b];
  #pragma unroll
  for(int j=0;j<4;j++){
    int i=base+j;
    if(i<N){ offs[i]=run; dinv[i]=rsqrtf((float)(c[j]+1u)); }
    run+=c[j];
  }
}

// atomic-free placement: position fully determined by offs + precomputed rank
__global__ void k_place(const int* __restrict__ src, const int* __restrict__ dst,
                        const unsigned* __restrict__ rank, const unsigned* __restrict__ offs,
                        int* __restrict__ csr, int E){
  int e=blockIdx.x*blockDim.x+threadIdx.x;
  if(e<E) csr[offs[dst[e]]+rank[e]]=src[e];
}

// weights: transpose+cast to bf16 [out][K] layout
__global__ void k_prepw(const float* __restrict__ W1,const float* __restrict__ Wl1,
                        const float* __restrict__ W2,const float* __restrict__ Wl2,
                        const float* __restrict__ Wm1,const float* __restrict__ Wm2,
                        unsigned short* __restrict__ Wt1, unsigned short* __restrict__ Wt2,
                        unsigned short* __restrict__ Wm1t, unsigned short* __restrict__ Wm2tp){
  int i=blockIdx.x*blockDim.x+threadIdx.x;
  if(i<256*128){
    int c=i>>7, k=i&127;
    float v1=(c<128)?W1[k*128+c]:Wl1[k*128+(c-128)];
    float v2=(c<128)?W2[k*128+c]:Wl2[k*128+(c-128)];
    Wt1[i]=f2bf(v1); Wt2[i]=f2bf(v2);
    if(c<128) Wm1t[i]=f2bf(Wm1[k*128+c]);
    if(c<16)  Wm2tp[i]=f2bf((c<10)?Wm2[k*10+c]:0.f);
  }
}

// GEMM: X[N][128] @ Wt[256][128]^T. Swapped-operand MFMA -> lane owns one
// node (l15) and 4 consecutive out-cols per acc reg -> packed 8B stores.
// cols 0..127: G = bf16(val*dinv[node]); cols 128..255: XL = bf16(val)
// FP32IN: read fp32 X and convert to bf16 fragments in-register (fused cast).
template<bool FP32IN>
__launch_bounds__(256)
__global__ void k_gemm(const void* __restrict__ Xv, const unsigned short* __restrict__ Wt,
                       const float* __restrict__ dinv,
                       unsigned short* __restrict__ G, unsigned short* __restrict__ XL, int N){
  int wave=threadIdx.x>>6, lane=threadIdx.x&63;
  int l15=lane&15, l4=lane>>4;
  int node0=blockIdx.x*64+wave*16;
  if(node0>=N) return;
  int arow=node0+l15; if(arow>N-1) arow=N-1;
  short8 a[4];
  if(FP32IN){
    const float* X=(const float*)Xv;
    #pragma unroll
    for(int ks=0;ks<4;ks++){
      float4 f0=*reinterpret_cast<const float4*>(X+(size_t)arow*128+ks*32+l4*8);
      float4 f1=*reinterpret_cast<const float4*>(X+(size_t)arow*128+ks*32+l4*8+4);
      short8 t;
      t[0]=(short)f2bf(f0.x); t[1]=(short)f2bf(f0.y); t[2]=(short)f2bf(f0.z); t[3]=(short)f2bf(f0.w);
      t[4]=(short)f2bf(f1.x); t[5]=(short)f2bf(f1.y); t[6]=(short)f2bf(f1.z); t[7]=(short)f2bf(f1.w);
      a[ks]=t;
    }
  }else{
    const unsigned short* X=(const unsigned short*)Xv;
    #pragma unroll
    for(int ks=0;ks<4;ks++)
      a[ks]=*reinterpret_cast<const short8*>(X+(size_t)arow*128+ks*32+l4*8);
  }
  f32x4 acc[16];
  #pragma unroll
  for(int ct=0;ct<16;ct++) acc[ct]=(f32x4){0.f,0.f,0.f,0.f};
  #pragma unroll
  for(int ct=0;ct<16;ct++){
    #pragma unroll
    for(int ks=0;ks<4;ks++){
      short8 bfr=*reinterpret_cast<const short8*>(Wt+(size_t)(ct*16+l15)*128+ks*32+l4*8);
      acc[ct]=__builtin_amdgcn_mfma_f32_16x16x32_bf16(bfr,a[ks],acc[ct],0,0,0);
    }
  }
  int node=node0+l15;
  if(node<N){
    float dv=dinv[node];
    #pragma unroll
    for(int ct=0;ct<8;ct++){
      f32x4 v=acc[ct];
      uint2 p; p.x=pack2(v[0]*dv,v[1]*dv); p.y=pack2(v[2]*dv,v[3]*dv);
      *reinterpret_cast<uint2*>(G+(size_t)node*128+ct*16+l4*4)=p;
    }
    #pragma unroll
    for(int ct=8;ct<16;ct++){
      f32x4 v=acc[ct];
      uint2 p; p.x=pack2(v[0],v[1]); p.y=pack2(v[2],v[3]);
      *reinterpret_cast<uint2*>(XL+(size_t)node*128+(ct-8)*16+l4*4)=p;
    }
  }
}

#define ADDROW(acc,v) do{ \
  unsigned _x=(unsigned)(v).x,_y=(unsigned)(v).y,_z=(unsigned)(v).z,_w=(unsigned)(v).w; \
  acc[0]+=bf2f((unsigned short)(_x&0xffffu)); acc[1]+=bf2f((unsigned short)(_x>>16)); \
  acc[2]+=bf2f((unsigned short)(_y&0xffffu)); acc[3]+=bf2f((unsigned short)(_y>>16)); \
  acc[4]+=bf2f((unsigned short)(_z&0xffffu)); acc[5]+=bf2f((unsigned short)(_z>>16)); \
  acc[6]+=bf2f((unsigned short)(_w&0xffffu)); acc[7]+=bf2f((unsigned short)(_w>>16)); }while(0)

// conv: one node per wave; 4 neighbor rows in flight per iteration.
// lane = (g=lane>>4 neighbor slot, li=lane&15 16B chunk of the 256B row).
// cross-group shfl_xor reduce; low=dinv*sum+b; out=0.5*low+0.5*xl (opt relu)
template<bool RELU>
__launch_bounds__(256)
__global__ void k_conv(const unsigned short* __restrict__ G, const unsigned short* __restrict__ XL,
                       const float* __restrict__ bias, const float* __restrict__ dinv,
                       const int* __restrict__ csr, const unsigned* __restrict__ offs,
                       const unsigned* __restrict__ cnt,
                       unsigned short* __restrict__ H, int N){
  int node=blockIdx.x*4+(threadIdx.x>>6);
  if(node>=N) return;
  int lane=threadIdx.x&63;
  int g=lane>>4, li=lane&15;
  const int4* Gv=(const int4*)G;
  float acc[8];
  #pragma unroll
  for(int i=0;i<8;i++) acc[i]=0.f;
  if(g==0){
    int4 v=Gv[(size_t)node*16+li];       // self-loop term
    ADDROW(acc,v);
  }
  unsigned start=offs[node], deg=cnt[node];
  unsigned j=(unsigned)g;
  if(j<deg){
    int4 v=Gv[(size_t)csr[start+j]*16+li];
    j+=4;
    while(j<deg){
      int4 vn=Gv[(size_t)csr[start+j]*16+li];
      ADDROW(acc,v);
      v=vn; j+=4;
    }
    ADDROW(acc,v);
  }
  #pragma unroll
  for(int i=0;i<8;i++){
    acc[i]+=__shfl_xor(acc[i],16,64);
    acc[i]+=__shfl_xor(acc[i],32,64);
  }
  if(g==0){
    float dv=dinv[node];
    float4 b0=*reinterpret_cast<const float4*>(bias+li*8);
    float4 b1=*reinterpret_cast<const float4*>(bias+li*8+4);
    int4 xv=((const int4*)XL)[(size_t)node*16+li];
    float xl[8];
    { unsigned _x=(unsigned)xv.x,_y=(unsigned)xv.y,_z=(unsigned)xv.z,_w=(unsigned)xv.w;
      xl[0]=bf2f((unsigned short)(_x&0xffffu)); xl[1]=bf2f((unsigned short)(_x>>16));
      xl[2]=bf2f((unsigned short)(_y&0xffffu)); xl[3]=bf2f((unsigned short)(_y>>16));
      xl[4]=bf2f((unsigned short)(_z&0xffffu)); xl[5]=bf2f((unsigned short)(_z>>16));
      xl[6]=bf2f((unsigned short)(_w&0xffffu)); xl[7]=bf2f((unsigned short)(_w>>16)); }
    float bb[8]={b0.x,b0.y,b0.z,b0.w,b1.x,b1.y,b1.z,b1.w};
    float r[8];
    #pragma unroll
    for(int i=0;i<8;i++){
      r[i]=0.5f*(dv*acc[i]+bb[i])+0.5f*xl[i];
      if(RELU) r[i]=fmaxf(r[i],0.f);
    }
    int4 o;
    o.x=(int)pack2(r[0],r[1]); o.y=(int)pack2(r[2],r[3]);
    o.z=(int)pack2(r[4],r[5]); o.w=(int)pack2(r[6],r[7]);
    ((int4*)H)[(size_t)node*16+li]=o;
  }
}

// MLP head: relu(H2@Wm1+bm1)@Wm2+bm2 -> injection -> log_softmax -> out
__launch_bounds__(256)
__global__ void k_mlp(const unsigned short* __restrict__ H2,
                      const unsigned short* __restrict__ Wm1t,
                      const unsigned short* __restrict__ Wm2tp,
                      const float* __restrict__ bm1, const float* __restrict__ bm2,
                      const unsigned char* __restrict__ flag, const float* __restrict__ preds,
                      float* __restrict__ out, int N){
  __shared__ __align__(16) unsigned short zt[4][16][136];  // +8 pad: kills 16-way LDS conflict
  __shared__ __align__(16) float lt[4][16][16];
  int wave=threadIdx.x>>6, lane=threadIdx.x&63;
  int l15=lane&15, l4=lane>>4;
  int node0=blockIdx.x*64+wave*16;
  int arow=node0+l15; if(arow>N-1) arow=N-1; if(arow<0) arow=0;
  short8 a[4];
  #pragma unroll
  for(int ks=0;ks<4;ks++)
    a[ks]=*reinterpret_cast<const short8*>(H2+(size_t)arow*128+ks*32+l4*8);
  f32x4 acc[8];
  #pragma unroll
  for(int ct=0;ct<8;ct++) acc[ct]=(f32x4){0.f,0.f,0.f,0.f};
  #pragma unroll
  for(int ct=0;ct<8;ct++){
    #pragma unroll
    for(int ks=0;ks<4;ks++){
      short8 bfr=*reinterpret_cast<const short8*>(Wm1t+(size_t)(ct*16+l15)*128+ks*32+l4*8);
      acc[ct]=__builtin_amdgcn_mfma_f32_16x16x32_bf16(bfr,a[ks],acc[ct],0,0,0);
    }
  }
  // lane holds node=l15, hid cols ct*16+l4*4..+3 -> packed 8B LDS writes
  #pragma unroll
  for(int ct=0;ct<8;ct++){
    float4 bm=*reinterpret_cast<const float4*>(bm1+ct*16+l4*4);
    uint2 p;
    p.x=pack2(fmaxf(acc[ct][0]+bm.x,0.f),fmaxf(acc[ct][1]+bm.y,0.f));
    p.y=pack2(fmaxf(acc[ct][2]+bm.z,0.f),fmaxf(acc[ct][3]+bm.w,0.f));
    *reinterpret_cast<uint2*>(&zt[wave][l15][ct*16+l4*4])=p;
  }
  __syncthreads();
  short8 a2[4];
  #pragma unroll
  for(int ks=0;ks<4;ks++)
    a2[ks]=*reinterpret_cast<const short8*>(&zt[wave][l15][ks*32+l4*8]);
  f32x4 acc2=(f32x4){0.f,0.f,0.f,0.f};
  #pragma unroll
  for(int ks=0;ks<4;ks++){
    short8 bfr=*reinterpret_cast<const short8*>(Wm2tp+(size_t)l15*128+ks*32+l4*8);
    acc2=__builtin_amdgcn_mfma_f32_16x16x32_bf16(bfr,a2[ks],acc2,0,0,0);
  }
  // lane holds node=l15, classes l4*4..+3
  *reinterpret_cast<f32x4*>(&lt[wave][l15][l4*4])=acc2;
  __syncthreads();
  if(lane<16){
    int node=node0+lane;
    if(node<N){
      float v[10];
      #pragma unroll
      for(int c=0;c<10;c++) v[c]=lt[wave][lane][c]+bm2[c];
      if(flag[node]){
        #pragma unroll
        for(int c=0;c<10;c++) v[c]+=INJ_LAM*preds[(size_t)node*10+c];
      }
      float m=v[0];
      #pragma unroll
      for(int c=1;c<10;c++) m=fmaxf(m,v[c]);
      float s=0.f;
      #pragma unroll
      for(int c=0;c<10;c++) s+=expf(v[c]-m);
      float lse=m+logf(s);
      #pragma unroll
      for(int c=0;c<10;c++) out[(size_t)node*10+c]=v[c]-lse;
    }
  }
}

extern "C" void kernel_launch(void* const* d_in, const int* in_sizes, int n_in,
                              void* d_out, int out_size, void* d_ws, size_t ws_size,
                              hipStream_t stream){
  const float* x    =(const float*)d_in[0];
  const int*   ei   =(const int*)  d_in[1];
  const int*   inj  =(const int*)  d_in[2];
  const float* preds=(const float*)d_in[3];
  const float* W1 =(const float*)d_in[4];  const float* b1 =(const float*)d_in[5];
  const float* W2 =(const float*)d_in[6];  const float* b2 =(const float*)d_in[7];
  const float* Wl1=(const float*)d_in[8];  const float* Wl2=(const float*)d_in[9];
  const float* Wm1=(const float*)d_in[10]; const float* bm1=(const float*)d_in[11];
  const float* Wm2=(const float*)d_in[12]; const float* bm2=(const float*)d_in[13];
  float* out=(float*)d_out;

  const int N  = in_sizes[0]/128;
  const int E  = in_sizes[1]/2;
  const int NI = in_sizes[2];
  const int* srcp = ei;
  const int* dstp = ei+E;

  char* w=(char*)d_ws;
  auto carve=[&](size_t sz)->char*{ char* p=w; w+=(sz+255)&~(size_t)255; return p; };
  unsigned short* S0 =(unsigned short*)carve((size_t)N*128*2); // hb -> h2b
  unsigned short* S1 =(unsigned short*)carve((size_t)N*128*2); // g1b -> g2b
  unsigned short* S2 =(unsigned short*)carve((size_t)N*128*2); // xl1b -> xl2b
  unsigned short* Wt1=(unsigned short*)carve(256*128*2);
  unsigned short* Wt2=(unsigned short*)carve(256*128*2);
  unsigned short* Wm1t=(unsigned short*)carve(128*128*2);
  unsigned short* Wm2tp=(unsigned short*)carve(16*128*2);
  unsigned* cnt   =(unsigned*)carve((size_t)N*4);
  float*    dinv  =(float*)   carve((size_t)N*4);
  unsigned* offs  =(unsigned*)carve((size_t)N*4);
  unsigned* rank  =(unsigned*)carve((size_t)E*4);
  int*      csr   =(int*)     carve((size_t)E*4);
  unsigned char* flags=(unsigned char*)carve(((size_t)N+3)&~(size_t)3);
  const int NB=(N+1023)/1024;
  unsigned* bsum=(unsigned*)carve((size_t)NB*4);
  unsigned* bo  =(unsigned*)carve((size_t)NB*4);
  (void)ws_size; (void)n_in; (void)out_size;

  const int T=256;
  hipMemsetAsync(cnt, 0, (size_t)N*4, stream);
  hipMemsetAsync(flags, 0, (size_t)N, stream);
  hipLaunchKernelGGL(k_count_mark, dim3((E+T-1)/T), dim3(T), 0, stream, dstp, cnt, rank, inj, flags, E, NI);
  hipLaunchKernelGGL(k_scan_a, dim3(NB), dim3(T), 0, stream, cnt, bsum, N);
  hipLaunchKernelGGL(k_scan_b, dim3(1), dim3(64), 0, stream, bsum, bo, NB);
  hipLaunchKernelGGL(k_scan_c, dim3(NB), dim3(T), 0, stream, cnt, bo, offs, dinv, N);
  hipLaunchKernelGGL(k_place, dim3((E+T-1)/T), dim3(T), 0, stream, srcp, dstp, rank, offs, csr, E);
  hipLaunchKernelGGL(k_prepw, dim3(128), dim3(T), 0, stream, W1,Wl1,W2,Wl2,Wm1,Wm2, Wt1,Wt2,Wm1t,Wm2tp);

  dim3 gemmGrid((N+63)/64);
  hipLaunchKernelGGL(k_gemm<true>,  gemmGrid, dim3(T), 0, stream, (const void*)x,  Wt1, dinv, S1, S2, N);
  hipLaunchKernelGGL(k_conv<true>,  dim3((N+3)/4), dim3(T), 0, stream, S1, S2, b1, dinv, csr, offs, cnt, S0, N);
  hipLaunchKernelGGL(k_gemm<false>, gemmGrid, dim3(T), 0, stream, (const void*)S0, Wt2, dinv, S1, S2, N);
  hipLaunchKernelGGL(k_conv<false>, dim3((N+3)/4), dim3(T), 0, stream, S1, S2, b2, dinv, csr, offs, cnt, S0, N);
  hipLaunchKernelGGL(k_mlp, gemmGrid, dim3(T), 0, stream, S0, Wm1t, Wm2tp, bm1, bm2, flags, preds, out, N);
}

// Round 4
// 368.888 us; speedup vs baseline: 1.9712x; 1.1551x over previous
//
#include <hip/hip_runtime.h>
#include <hip/hip_bf16.h>
#include <math.h>

typedef __attribute__((ext_vector_type(8))) short short8;
typedef __attribute__((ext_vector_type(4))) float f32x4;

#define INJ_LAM 0.8f

__device__ inline float bf2f(unsigned short s){
  union{unsigned u; float f;} v; v.u=((unsigned)s)<<16; return v.f;
}
__device__ inline unsigned short f2bf(float f){
  __hip_bfloat16 h=__float2bfloat16(f);
  return *reinterpret_cast<unsigned short*>(&h);
}
__device__ inline unsigned pack2(float lo, float hi){
  return ((unsigned)f2bf(hi)<<16)|(unsigned)f2bf(lo);
}

// count degrees; atomic return value IS the edge's rank within its dst segment.
__global__ void k_count_mark(const int* __restrict__ dst, unsigned* __restrict__ cnt,
                             unsigned* __restrict__ rank,
                             const int* __restrict__ inj, unsigned char* __restrict__ flag,
                             int E, int NI){
  int i=blockIdx.x*blockDim.x+threadIdx.x;
  if(i<E) rank[i]=atomicAdd(&cnt[dst[i]],1u);
  if(i<NI) flag[inj[i]]=1;
}

// ---- scan over per-node counts -> CSR offsets (1024 counts per block) ----
__global__ void k_scan_a(const unsigned* __restrict__ cnt, unsigned* __restrict__ bsum, int N){
  __shared__ unsigned sh[256];
  int t=threadIdx.x, b=blockIdx.x;
  int base=b*1024+t*4;
  unsigned ts=0;
  #pragma unroll
  for(int j=0;j<4;j++){ int i=base+j; if(i<N) ts+=cnt[i]; }
  sh[t]=ts; __syncthreads();
  for(int off=128;off>0;off>>=1){ if(t<off) sh[t]+=sh[t+off]; __syncthreads(); }
  if(t==0) bsum[b]=sh[0];
}

__global__ void k_scan_b(const unsigned* __restrict__ bsum, unsigned* __restrict__ bo, int NB){
  if(threadIdx.x==0 && blockIdx.x==0){
    unsigned run=0;
    for(int i=0;i<NB;i++){ bo[i]=run; run+=bsum[i]; }
  }
}

__global__ void k_scan_c(const unsigned* __restrict__ cnt, const unsigned* __restrict__ bo,
                         unsigned* __restrict__ offs,
                         float* __restrict__ dinv, int N){
  __shared__ unsigned sh[256];
  int t=threadIdx.x, b=blockIdx.x;
  int base=b*1024+t*4;
  unsigned c[4]; unsigned ts=0;
  #pragma unroll
  for(int j=0;j<4;j++){ int i=base+j; c[j]=(i<N)?cnt[i]:0u; ts+=c[j]; }
  sh[t]=ts; __syncthreads();
  for(int off=1;off<256;off<<=1){
    unsigned v=(t>=off)?sh[t-off]:0u; __syncthreads();
    sh[t]+=v; __syncthreads();
  }
  unsigned run=sh[t]-ts+bo[b];
  #pragma unroll
  for(int j=0;j<4;j++){
    int i=base+j;
    if(i<N){ offs[i]=run; dinv[i]=rsqrtf((float)(c[j]+1u)); }
    run+=c[j];
  }
}

// atomic-free placement: position fully determined by offs + precomputed rank
__global__ void k_place(const int* __restrict__ src, const int* __restrict__ dst,
                        const unsigned* __restrict__ rank, const unsigned* __restrict__ offs,
                        int* __restrict__ csr, int E){
  int e=blockIdx.x*blockDim.x+threadIdx.x;
  if(e<E) csr[offs[dst[e]]+rank[e]]=src[e];
}

// weights: transpose+cast to bf16 [out][K] layout
__global__ void k_prepw(const float* __restrict__ W1,const float* __restrict__ Wl1,
                        const float* __restrict__ W2,const float* __restrict__ Wl2,
                        const float* __restrict__ Wm1,const float* __restrict__ Wm2,
                        unsigned short* __restrict__ Wt1, unsigned short* __restrict__ Wt2,
                        unsigned short* __restrict__ Wm1t, unsigned short* __restrict__ Wm2tp){
  int i=blockIdx.x*blockDim.x+threadIdx.x;
  if(i<256*128){
    int c=i>>7, k=i&127;
    float v1=(c<128)?W1[k*128+c]:Wl1[k*128+(c-128)];
    float v2=(c<128)?W2[k*128+c]:Wl2[k*128+(c-128)];
    Wt1[i]=f2bf(v1); Wt2[i]=f2bf(v2);
    if(c<128) Wm1t[i]=f2bf(Wm1[k*128+c]);
    if(c<16)  Wm2tp[i]=f2bf((c<10)?Wm2[k*10+c]:0.f);
  }
}

template<bool FP32IN>
__device__ inline void load_afrag(const void* __restrict__ Xv, size_t arow, int l4, short8* a){
  if(FP32IN){
    const float* X=(const float*)Xv + arow*128 + l4*8;
    #pragma unroll
    for(int ks=0;ks<4;ks++){
      float4 f0=*reinterpret_cast<const float4*>(X+ks*32);
      float4 f1=*reinterpret_cast<const float4*>(X+ks*32+4);
      short8 t;
      t[0]=(short)f2bf(f0.x); t[1]=(short)f2bf(f0.y); t[2]=(short)f2bf(f0.z); t[3]=(short)f2bf(f0.w);
      t[4]=(short)f2bf(f1.x); t[5]=(short)f2bf(f1.y); t[6]=(short)f2bf(f1.z); t[7]=(short)f2bf(f1.w);
      a[ks]=t;
    }
  }else{
    const unsigned short* X=(const unsigned short*)Xv + arow*128 + l4*8;
    #pragma unroll
    for(int ks=0;ks<4;ks++)
      a[ks]=*reinterpret_cast<const short8*>(X+ks*32);
  }
}

// GEMM: X[N][128] @ Wt[256][128]^T, 128 nodes/block, 4 waves.
// Wave w keeps out-col tiles ct=4w..4w+3 weight fragments in REGISTERS
// (loaded once/block); node tiles stream with a 2-stage A-fragment pipeline.
// Output lane mapping per mfma(wf,a): lane -> node=node0+l15, cols ct*16+l4*4..+3.
// Waves 0-1 -> G (xdinv), waves 2-3 -> XL.
template<bool FP32IN>
__launch_bounds__(256, 4)
__global__ void k_gemm(const void* __restrict__ Xv, const unsigned short* __restrict__ Wt,
                       const float* __restrict__ dinv,
                       unsigned short* __restrict__ G, unsigned short* __restrict__ XL, int N){
  int wave=threadIdx.x>>6, lane=threadIdx.x&63;
  int l15=lane&15, l4=lane>>4;
  int blk0=blockIdx.x*128;
  if(blk0>=N) return;
  short8 wf[4][4];
  #pragma unroll
  for(int i=0;i<4;i++){
    int col=(wave*4+i)*16+l15;
    #pragma unroll
    for(int ks=0;ks<4;ks++)
      wf[i][ks]=*reinterpret_cast<const short8*>(Wt+(size_t)col*128+ks*32+l4*8);
  }
  int r0=blk0+l15; if(r0>N-1) r0=N-1;
  short8 aC[4], aN[4];
  load_afrag<FP32IN>(Xv,(size_t)r0,l4,aC);
  #pragma unroll 1
  for(int nt=0;nt<8;nt++){
    int node0=blk0+nt*16;
    if(node0>=N) break;
    if(nt<7){
      int rn=node0+16+l15; if(rn>N-1) rn=N-1;
      load_afrag<FP32IN>(Xv,(size_t)rn,l4,aN);
    }
    f32x4 acc[4];
    #pragma unroll
    for(int i=0;i<4;i++) acc[i]=(f32x4){0.f,0.f,0.f,0.f};
    #pragma unroll
    for(int i=0;i<4;i++){
      #pragma unroll
      for(int ks=0;ks<4;ks++)
        acc[i]=__builtin_amdgcn_mfma_f32_16x16x32_bf16(wf[i][ks],aC[ks],acc[i],0,0,0);
    }
    int node=node0+l15;
    if(node<N){
      if(wave<2){
        float dv=dinv[node];
        #pragma unroll
        for(int i=0;i<4;i++){
          f32x4 v=acc[i];
          uint2 p; p.x=pack2(v[0]*dv,v[1]*dv); p.y=pack2(v[2]*dv,v[3]*dv);
          *reinterpret_cast<uint2*>(G+(size_t)node*128+(wave*4+i)*16+l4*4)=p;
        }
      }else{
        #pragma unroll
        for(int i=0;i<4;i++){
          f32x4 v=acc[i];
          uint2 p; p.x=pack2(v[0],v[1]); p.y=pack2(v[2],v[3]);
          *reinterpret_cast<uint2*>(XL+(size_t)node*128+((wave-2)*4+i)*16+l4*4)=p;
        }
      }
    }
    #pragma unroll
    for(int ks=0;ks<4;ks++) aC[ks]=aN[ks];
  }
}

#define ADDROW(acc,v) do{ \
  unsigned _x=(unsigned)(v).x,_y=(unsigned)(v).y,_z=(unsigned)(v).z,_w=(unsigned)(v).w; \
  acc[0]+=bf2f((unsigned short)(_x&0xffffu)); acc[1]+=bf2f((unsigned short)(_x>>16)); \
  acc[2]+=bf2f((unsigned short)(_y&0xffffu)); acc[3]+=bf2f((unsigned short)(_y>>16)); \
  acc[4]+=bf2f((unsigned short)(_z&0xffffu)); acc[5]+=bf2f((unsigned short)(_z>>16)); \
  acc[6]+=bf2f((unsigned short)(_w&0xffffu)); acc[7]+=bf2f((unsigned short)(_w>>16)); }while(0)

// conv: one node per wave; 4 neighbor rows in flight per iteration.
template<bool RELU>
__launch_bounds__(256)
__global__ void k_conv(const unsigned short* __restrict__ G, const unsigned short* __restrict__ XL,
                       const float* __restrict__ bias, const float* __restrict__ dinv,
                       const int* __restrict__ csr, const unsigned* __restrict__ offs,
                       const unsigned* __restrict__ cnt,
                       unsigned short* __restrict__ H, int N){
  int node=blockIdx.x*4+(threadIdx.x>>6);
  if(node>=N) return;
  int lane=threadIdx.x&63;
  int g=lane>>4, li=lane&15;
  const int4* Gv=(const int4*)G;
  float acc[8];
  #pragma unroll
  for(int i=0;i<8;i++) acc[i]=0.f;
  if(g==0){
    int4 v=Gv[(size_t)node*16+li];       // self-loop term
    ADDROW(acc,v);
  }
  unsigned start=offs[node], deg=cnt[node];
  unsigned j=(unsigned)g;
  if(j<deg){
    int4 v=Gv[(size_t)csr[start+j]*16+li];
    j+=4;
    while(j<deg){
      int4 vn=Gv[(size_t)csr[start+j]*16+li];
      ADDROW(acc,v);
      v=vn; j+=4;
    }
    ADDROW(acc,v);
  }
  #pragma unroll
  for(int i=0;i<8;i++){
    acc[i]+=__shfl_xor(acc[i],16,64);
    acc[i]+=__shfl_xor(acc[i],32,64);
  }
  if(g==0){
    float dv=dinv[node];
    float4 b0=*reinterpret_cast<const float4*>(bias+li*8);
    float4 b1=*reinterpret_cast<const float4*>(bias+li*8+4);
    int4 xv=((const int4*)XL)[(size_t)node*16+li];
    float xl[8];
    { unsigned _x=(unsigned)xv.x,_y=(unsigned)xv.y,_z=(unsigned)xv.z,_w=(unsigned)xv.w;
      xl[0]=bf2f((unsigned short)(_x&0xffffu)); xl[1]=bf2f((unsigned short)(_x>>16));
      xl[2]=bf2f((unsigned short)(_y&0xffffu)); xl[3]=bf2f((unsigned short)(_y>>16));
      xl[4]=bf2f((unsigned short)(_z&0xffffu)); xl[5]=bf2f((unsigned short)(_z>>16));
      xl[6]=bf2f((unsigned short)(_w&0xffffu)); xl[7]=bf2f((unsigned short)(_w>>16)); }
    float bb[8]={b0.x,b0.y,b0.z,b0.w,b1.x,b1.y,b1.z,b1.w};
    float r[8];
    #pragma unroll
    for(int i=0;i<8;i++){
      r[i]=0.5f*(dv*acc[i]+bb[i])+0.5f*xl[i];
      if(RELU) r[i]=fmaxf(r[i],0.f);
    }
    int4 o;
    o.x=(int)pack2(r[0],r[1]); o.y=(int)pack2(r[2],r[3]);
    o.z=(int)pack2(r[4],r[5]); o.w=(int)pack2(r[6],r[7]);
    ((int4*)H)[(size_t)node*16+li]=o;
  }
}

// MLP head: relu(H2@Wm1+bm1)@Wm2+bm2 -> injection -> log_softmax -> out
__launch_bounds__(256)
__global__ void k_mlp(const unsigned short* __restrict__ H2,
                      const unsigned short* __restrict__ Wm1t,
                      const unsigned short* __restrict__ Wm2tp,
                      const float* __restrict__ bm1, const float* __restrict__ bm2,
                      const unsigned char* __restrict__ flag, const float* __restrict__ preds,
                      float* __restrict__ out, int N){
  __shared__ __align__(16) unsigned short zt[4][16][136];  // +8 pad: kills 16-way LDS conflict
  __shared__ __align__(16) float lt[4][16][16];
  int wave=threadIdx.x>>6, lane=threadIdx.x&63;
  int l15=lane&15, l4=lane>>4;
  int node0=blockIdx.x*64+wave*16;
  int arow=node0+l15; if(arow>N-1) arow=N-1; if(arow<0) arow=0;
  short8 a[4];
  #pragma unroll
  for(int ks=0;ks<4;ks++)
    a[ks]=*reinterpret_cast<const short8*>(H2+(size_t)arow*128+ks*32+l4*8);
  f32x4 acc[8];
  #pragma unroll
  for(int ct=0;ct<8;ct++) acc[ct]=(f32x4){0.f,0.f,0.f,0.f};
  #pragma unroll
  for(int ct=0;ct<8;ct++){
    #pragma unroll
    for(int ks=0;ks<4;ks++){
      short8 bfr=*reinterpret_cast<const short8*>(Wm1t+(size_t)(ct*16+l15)*128+ks*32+l4*8);
      acc[ct]=__builtin_amdgcn_mfma_f32_16x16x32_bf16(bfr,a[ks],acc[ct],0,0,0);
    }
  }
  // lane holds node=l15, hid cols ct*16+l4*4..+3 -> packed 8B LDS writes
  #pragma unroll
  for(int ct=0;ct<8;ct++){
    float4 bm=*reinterpret_cast<const float4*>(bm1+ct*16+l4*4);
    uint2 p;
    p.x=pack2(fmaxf(acc[ct][0]+bm.x,0.f),fmaxf(acc[ct][1]+bm.y,0.f));
    p.y=pack2(fmaxf(acc[ct][2]+bm.z,0.f),fmaxf(acc[ct][3]+bm.w,0.f));
    *reinterpret_cast<uint2*>(&zt[wave][l15][ct*16+l4*4])=p;
  }
  __syncthreads();
  short8 a2[4];
  #pragma unroll
  for(int ks=0;ks<4;ks++)
    a2[ks]=*reinterpret_cast<const short8*>(&zt[wave][l15][ks*32+l4*8]);
  f32x4 acc2=(f32x4){0.f,0.f,0.f,0.f};
  #pragma unroll
  for(int ks=0;ks<4;ks++){
    short8 bfr=*reinterpret_cast<const short8*>(Wm2tp+(size_t)l15*128+ks*32+l4*8);
    acc2=__builtin_amdgcn_mfma_f32_16x16x32_bf16(bfr,a2[ks],acc2,0,0,0);
  }
  // lane holds node=l15, classes l4*4..+3
  *reinterpret_cast<f32x4*>(&lt[wave][l15][l4*4])=acc2;
  __syncthreads();
  if(lane<16){
    int node=node0+lane;
    if(node<N){
      float v[10];
      #pragma unroll
      for(int c=0;c<10;c++) v[c]=lt[wave][lane][c]+bm2[c];
      if(flag[node]){
        #pragma unroll
        for(int c=0;c<10;c++) v[c]+=INJ_LAM*preds[(size_t)node*10+c];
      }
      float m=v[0];
      #pragma unroll
      for(int c=1;c<10;c++) m=fmaxf(m,v[c]);
      float s=0.f;
      #pragma unroll
      for(int c=0;c<10;c++) s+=expf(v[c]-m);
      float lse=m+logf(s);
      #pragma unroll
      for(int c=0;c<10;c++) out[(size_t)node*10+c]=v[c]-lse;
    }
  }
}

extern "C" void kernel_launch(void* const* d_in, const int* in_sizes, int n_in,
                              void* d_out, int out_size, void* d_ws, size_t ws_size,
                              hipStream_t stream){
  const float* x    =(const float*)d_in[0];
  const int*   ei   =(const int*)  d_in[1];
  const int*   inj  =(const int*)  d_in[2];
  const float* preds=(const float*)d_in[3];
  const float* W1 =(const float*)d_in[4];  const float* b1 =(const float*)d_in[5];
  const float* W2 =(const float*)d_in[6];  const float* b2 =(const float*)d_in[7];
  const float* Wl1=(const float*)d_in[8];  const float* Wl2=(const float*)d_in[9];
  const float* Wm1=(const float*)d_in[10]; const float* bm1=(const float*)d_in[11];
  const float* Wm2=(const float*)d_in[12]; const float* bm2=(const float*)d_in[13];
  float* out=(float*)d_out;

  const int N  = in_sizes[0]/128;
  const int E  = in_sizes[1]/2;
  const int NI = in_sizes[2];
  const int* srcp = ei;
  const int* dstp = ei+E;

  char* w=(char*)d_ws;
  auto carve=[&](size_t sz)->char*{ char* p=w; w+=(sz+255)&~(size_t)255; return p; };
  unsigned short* S0 =(unsigned short*)carve((size_t)N*128*2); // hb -> h2b
  unsigned short* S1 =(unsigned short*)carve((size_t)N*128*2); // g1b -> g2b
  unsigned short* S2 =(unsigned short*)carve((size_t)N*128*2); // xl1b -> xl2b
  unsigned short* Wt1=(unsigned short*)carve(256*128*2);
  unsigned short* Wt2=(unsigned short*)carve(256*128*2);
  unsigned short* Wm1t=(unsigned short*)carve(128*128*2);
  unsigned short* Wm2tp=(unsigned short*)carve(16*128*2);
  unsigned* cnt   =(unsigned*)carve((size_t)N*4);
  float*    dinv  =(float*)   carve((size_t)N*4);
  unsigned* offs  =(unsigned*)carve((size_t)N*4);
  unsigned* rank  =(unsigned*)carve((size_t)E*4);
  int*      csr   =(int*)     carve((size_t)E*4);
  unsigned char* flags=(unsigned char*)carve(((size_t)N+3)&~(size_t)3);
  const int NB=(N+1023)/1024;
  unsigned* bsum=(unsigned*)carve((size_t)NB*4);
  unsigned* bo  =(unsigned*)carve((size_t)NB*4);
  (void)ws_size; (void)n_in; (void)out_size;

  const int T=256;
  hipMemsetAsync(cnt, 0, (size_t)N*4, stream);
  hipMemsetAsync(flags, 0, (size_t)N, stream);
  hipLaunchKernelGGL(k_count_mark, dim3((E+T-1)/T), dim3(T), 0, stream, dstp, cnt, rank, inj, flags, E, NI);
  hipLaunchKernelGGL(k_scan_a, dim3(NB), dim3(T), 0, stream, cnt, bsum, N);
  hipLaunchKernelGGL(k_scan_b, dim3(1), dim3(64), 0, stream, bsum, bo, NB);
  hipLaunchKernelGGL(k_scan_c, dim3(NB), dim3(T), 0, stream, cnt, bo, offs, dinv, N);
  hipLaunchKernelGGL(k_place, dim3((E+T-1)/T), dim3(T), 0, stream, srcp, dstp, rank, offs, csr, E);
  hipLaunchKernelGGL(k_prepw, dim3(128), dim3(T), 0, stream, W1,Wl1,W2,Wl2,Wm1,Wm2, Wt1,Wt2,Wm1t,Wm2tp);

  dim3 gemmGrid((N+127)/128);
  hipLaunchKernelGGL(k_gemm<true>,  gemmGrid, dim3(T), 0, stream, (const void*)x,  Wt1, dinv, S1, S2, N);
  hipLaunchKernelGGL(k_conv<true>,  dim3((N+3)/4), dim3(T), 0, stream, S1, S2, b1, dinv, csr, offs, cnt, S0, N);
  hipLaunchKernelGGL(k_gemm<false>, gemmGrid, dim3(T), 0, stream, (const void*)S0, Wt2, dinv, S1, S2, N);
  hipLaunchKernelGGL(k_conv<false>, dim3((N+3)/4), dim3(T), 0, stream, S1, S2, b2, dinv, csr, offs, cnt, S0, N);
  hipLaunchKernelGGL(k_mlp, dim3((N+63)/64), dim3(T), 0, stream, S0, Wm1t, Wm2tp, bm1, bm2, flags, preds, out, N);
}

// Round 5
// 353.877 us; speedup vs baseline: 2.0548x; 1.0424x over previous
//
#include <hip/hip_runtime.h>
#include <hip/hip_bf16.h>
#include <math.h>

typedef __attribute__((ext_vector_type(8))) short short8;
typedef __attribute__((ext_vector_type(4))) float f32x4;

#define INJ_LAM 0.8f
#define BSH 9
#define BWD 512   // nodes per bucket

__device__ inline float bf2f(unsigned short s){
  union{unsigned u; float f;} v; v.u=((unsigned)s)<<16; return v.f;
}
__device__ inline unsigned short f2bf(float f){
  __hip_bfloat16 h=__float2bfloat16(f);
  return *reinterpret_cast<unsigned short*>(&h);
}
__device__ inline unsigned pack2(float lo, float hi){
  return ((unsigned)f2bf(hi)<<16)|(unsigned)f2bf(lo);
}

// ---- bucketed CSR build (no per-edge global atomics) ----
// bhist: per-block LDS hist of dst>>BSH, padded-sector global merge; also inject flags
__global__ void k_bhist(const int* __restrict__ dst, unsigned* __restrict__ bhist8,
                        const int* __restrict__ inj, unsigned char* __restrict__ flag,
                        int E, int NI){
  __shared__ unsigned lh[256];
  int t=threadIdx.x;
  lh[t]=0u;
  int i=blockIdx.x*256+t;
  if(i<NI) flag[inj[i]]=1;
  __syncthreads();
  int base=blockIdx.x*2048;
  #pragma unroll
  for(int k=0;k<8;k++){
    int e=base+k*256+t;
    if(e<E) atomicAdd(&lh[dst[e]>>BSH],1u);
  }
  __syncthreads();
  if(lh[t]) atomicAdd(&bhist8[t*8],lh[t]);
}

// bscan: one block; exclusive prefix over bucket totals -> bbase, init padded cursors
__global__ void k_bscan(const unsigned* __restrict__ bhist8, unsigned* __restrict__ bbase,
                        unsigned* __restrict__ bcur8, int NBK){
  __shared__ unsigned ss[256];
  int t=threadIdx.x;
  unsigned v=(t<NBK)?bhist8[t*8]:0u;
  ss[t]=v; __syncthreads();
  for(int off=1;off<256;off<<=1){
    unsigned u=(t>=off)?ss[t-off]:0u; __syncthreads();
    ss[t]+=u; __syncthreads();
  }
  unsigned excl=ss[t]-v;
  if(t<NBK){ bbase[t]=excl; bcur8[t*8]=excl; }
  if(t==255) bbase[NBK]=ss[255];
}

// bscatter: group edges by bucket. LDS local rank + per-bucket block reservation.
__global__ void k_bscatter(const int* __restrict__ src, const int* __restrict__ dst,
                           unsigned* __restrict__ bcur8,
                           int* __restrict__ psrc, int* __restrict__ pdst, int E){
  __shared__ unsigned lh[256];
  __shared__ unsigned gb[256];
  int t=threadIdx.x;
  lh[t]=0u; __syncthreads();
  int base=blockIdx.x*2048;
  unsigned lr[8]; int bk[8], sv[8], dv_[8];
  #pragma unroll
  for(int k=0;k<8;k++){
    int e=base+k*256+t;
    if(e<E){
      int d=dst[e]; int b=d>>BSH;
      bk[k]=b; dv_[k]=d; sv[k]=src[e];
      lr[k]=atomicAdd(&lh[b],1u);
    } else bk[k]=-1;
  }
  __syncthreads();
  if(lh[t]) gb[t]=atomicAdd(&bcur8[t*8],lh[t]);
  __syncthreads();
  #pragma unroll
  for(int k=0;k<8;k++){
    if(bk[k]>=0){
      unsigned p=gb[bk[k]]+lr[k];
      psrc[p]=sv[k]; pdst[p]=dv_[k];
    }
  }
}

// bucket: one block per bucket. Exact per-node cnt+rank via LDS atomics,
// LDS scan -> offs, write csr (random writes confined to L2-resident region),
// plus cnt/offs/dinv (coalesced).
__launch_bounds__(256)
__global__ void k_bucket(const int* __restrict__ psrc, const int* __restrict__ pdst,
                         const unsigned* __restrict__ bbase, unsigned* __restrict__ rank,
                         unsigned* __restrict__ cnt, unsigned* __restrict__ offs,
                         float* __restrict__ dinv, int* __restrict__ csr, int N){
  __shared__ unsigned lc[BWD];
  __shared__ unsigned lo[BWD];
  __shared__ unsigned ss[256];
  int b=blockIdx.x, t=threadIdx.x;
  unsigned e0=bbase[b], e1=bbase[b+1];
  int lo_node=b<<BSH;
  lc[t]=0u; lc[t+256]=0u; __syncthreads();
  for(unsigned p=e0+t;p<e1;p+=256){
    int dl=pdst[p]-lo_node;
    rank[p]=atomicAdd(&lc[dl],1u);
  }
  __syncthreads();
  unsigned c0=lc[2*t], c1=lc[2*t+1], ps=c0+c1;
  ss[t]=ps; __syncthreads();
  for(int off=1;off<256;off<<=1){
    unsigned u=(t>=off)?ss[t-off]:0u; __syncthreads();
    ss[t]+=u; __syncthreads();
  }
  unsigned excl=ss[t]-ps;
  lo[2*t]=excl; lo[2*t+1]=excl+c0;
  __syncthreads();
  #pragma unroll
  for(int k=0;k<2;k++){
    int nl=t+k*256; int node=lo_node+nl;
    if(node<N){
      unsigned c=lc[nl];
      cnt[node]=c;
      offs[node]=e0+lo[nl];
      dinv[node]=rsqrtf((float)(c+1u));
    }
  }
  for(unsigned p=e0+t;p<e1;p+=256){
    int dl=pdst[p]-lo_node;
    csr[e0+lo[dl]+rank[p]]=psrc[p];
  }
}

// weights: transpose+cast to bf16 [out][K] layout
__global__ void k_prepw(const float* __restrict__ W1,const float* __restrict__ Wl1,
                        const float* __restrict__ W2,const float* __restrict__ Wl2,
                        const float* __restrict__ Wm1,const float* __restrict__ Wm2,
                        unsigned short* __restrict__ Wt1, unsigned short* __restrict__ Wt2,
                        unsigned short* __restrict__ Wm1t, unsigned short* __restrict__ Wm2tp){
  int i=blockIdx.x*blockDim.x+threadIdx.x;
  if(i<256*128){
    int c=i>>7, k=i&127;
    float v1=(c<128)?W1[k*128+c]:Wl1[k*128+(c-128)];
    float v2=(c<128)?W2[k*128+c]:Wl2[k*128+(c-128)];
    Wt1[i]=f2bf(v1); Wt2[i]=f2bf(v2);
    if(c<128) Wm1t[i]=f2bf(Wm1[k*128+c]);
    if(c<16)  Wm2tp[i]=f2bf((c<10)?Wm2[k*10+c]:0.f);
  }
}

template<bool FP32IN>
__device__ inline void load_afrag(const void* __restrict__ Xv, size_t arow, int l4, short8* a){
  if(FP32IN){
    const float* X=(const float*)Xv + arow*128 + l4*8;
    #pragma unroll
    for(int ks=0;ks<4;ks++){
      float4 f0=*reinterpret_cast<const float4*>(X+ks*32);
      float4 f1=*reinterpret_cast<const float4*>(X+ks*32+4);
      short8 t;
      t[0]=(short)f2bf(f0.x); t[1]=(short)f2bf(f0.y); t[2]=(short)f2bf(f0.z); t[3]=(short)f2bf(f0.w);
      t[4]=(short)f2bf(f1.x); t[5]=(short)f2bf(f1.y); t[6]=(short)f2bf(f1.z); t[7]=(short)f2bf(f1.w);
      a[ks]=t;
    }
  }else{
    const unsigned short* X=(const unsigned short*)Xv + arow*128 + l4*8;
    #pragma unroll
    for(int ks=0;ks<4;ks++)
      a[ks]=*reinterpret_cast<const short8*>(X+ks*32);
  }
}

// GEMM: weights in registers (loaded once/block); node tiles stream, 2-stage pipeline.
template<bool FP32IN>
__launch_bounds__(256, 4)
__global__ void k_gemm(const void* __restrict__ Xv, const unsigned short* __restrict__ Wt,
                       const float* __restrict__ dinv,
                       unsigned short* __restrict__ G, unsigned short* __restrict__ XL, int N){
  int wave=threadIdx.x>>6, lane=threadIdx.x&63;
  int l15=lane&15, l4=lane>>4;
  int blk0=blockIdx.x*128;
  if(blk0>=N) return;
  short8 wf[4][4];
  #pragma unroll
  for(int i=0;i<4;i++){
    int col=(wave*4+i)*16+l15;
    #pragma unroll
    for(int ks=0;ks<4;ks++)
      wf[i][ks]=*reinterpret_cast<const short8*>(Wt+(size_t)col*128+ks*32+l4*8);
  }
  int r0=blk0+l15; if(r0>N-1) r0=N-1;
  short8 aC[4], aN[4];
  load_afrag<FP32IN>(Xv,(size_t)r0,l4,aC);
  #pragma unroll 1
  for(int nt=0;nt<8;nt++){
    int node0=blk0+nt*16;
    if(node0>=N) break;
    if(nt<7){
      int rn=node0+16+l15; if(rn>N-1) rn=N-1;
      load_afrag<FP32IN>(Xv,(size_t)rn,l4,aN);
    }
    f32x4 acc[4];
    #pragma unroll
    for(int i=0;i<4;i++) acc[i]=(f32x4){0.f,0.f,0.f,0.f};
    #pragma unroll
    for(int i=0;i<4;i++){
      #pragma unroll
      for(int ks=0;ks<4;ks++)
        acc[i]=__builtin_amdgcn_mfma_f32_16x16x32_bf16(wf[i][ks],aC[ks],acc[i],0,0,0);
    }
    int node=node0+l15;
    if(node<N){
      if(wave<2){
        float dv=dinv[node];
        #pragma unroll
        for(int i=0;i<4;i++){
          f32x4 v=acc[i];
          uint2 p; p.x=pack2(v[0]*dv,v[1]*dv); p.y=pack2(v[2]*dv,v[3]*dv);
          *reinterpret_cast<uint2*>(G+(size_t)node*128+(wave*4+i)*16+l4*4)=p;
        }
      }else{
        #pragma unroll
        for(int i=0;i<4;i++){
          f32x4 v=acc[i];
          uint2 p; p.x=pack2(v[0],v[1]); p.y=pack2(v[2],v[3]);
          *reinterpret_cast<uint2*>(XL+(size_t)node*128+((wave-2)*4+i)*16+l4*4)=p;
        }
      }
    }
    #pragma unroll
    for(int ks=0;ks<4;ks++) aC[ks]=aN[ks];
  }
}

#define ADDROW(acc,v) do{ \
  unsigned _x=(unsigned)(v).x,_y=(unsigned)(v).y,_z=(unsigned)(v).z,_w=(unsigned)(v).w; \
  acc[0]+=bf2f((unsigned short)(_x&0xffffu)); acc[1]+=bf2f((unsigned short)(_x>>16)); \
  acc[2]+=bf2f((unsigned short)(_y&0xffffu)); acc[3]+=bf2f((unsigned short)(_y>>16)); \
  acc[4]+=bf2f((unsigned short)(_z&0xffffu)); acc[5]+=bf2f((unsigned short)(_z>>16)); \
  acc[6]+=bf2f((unsigned short)(_w&0xffffu)); acc[7]+=bf2f((unsigned short)(_w>>16)); }while(0)

// conv: one node per wave; 8 rows in flight (2 per 16-lane group, pipelined).
template<bool RELU>
__launch_bounds__(256)
__global__ void k_conv(const unsigned short* __restrict__ G, const unsigned short* __restrict__ XL,
                       const float* __restrict__ bias, const float* __restrict__ dinv,
                       const int* __restrict__ csr, const unsigned* __restrict__ offs,
                       const unsigned* __restrict__ cnt,
                       unsigned short* __restrict__ H, int N){
  int node=blockIdx.x*4+(threadIdx.x>>6);
  if(node>=N) return;
  int lane=threadIdx.x&63;
  int g=lane>>4, li=lane&15;
  const int4* Gv=(const int4*)G;
  const int4 Z={0,0,0,0};
  float acc[8];
  #pragma unroll
  for(int i=0;i<8;i++) acc[i]=0.f;
  if(g==0){
    int4 v=Gv[(size_t)node*16+li];       // self-loop term
    ADDROW(acc,v);
  }
  unsigned start=offs[node], deg=cnt[node];
  unsigned j=(unsigned)g;
  int4 v0=Z, v1=Z;
  if(j<deg)   v0=Gv[(size_t)csr[start+j]*16+li];
  if(j+4<deg) v1=Gv[(size_t)csr[start+j+4]*16+li];
  j+=8;
  while(j<deg){
    int4 w0=Gv[(size_t)csr[start+j]*16+li];
    int4 w1=(j+4<deg)?Gv[(size_t)csr[start+j+4]*16+li]:Z;
    ADDROW(acc,v0); ADDROW(acc,v1);
    v0=w0; v1=w1; j+=8;
  }
  ADDROW(acc,v0); ADDROW(acc,v1);
  #pragma unroll
  for(int i=0;i<8;i++){
    acc[i]+=__shfl_xor(acc[i],16,64);
    acc[i]+=__shfl_xor(acc[i],32,64);
  }
  if(g==0){
    float dv=dinv[node];
    float4 b0=*reinterpret_cast<const float4*>(bias+li*8);
    float4 b1=*reinterpret_cast<const float4*>(bias+li*8+4);
    int4 xv=((const int4*)XL)[(size_t)node*16+li];
    float xl[8];
    { unsigned _x=(unsigned)xv.x,_y=(unsigned)xv.y,_z=(unsigned)xv.z,_w=(unsigned)xv.w;
      xl[0]=bf2f((unsigned short)(_x&0xffffu)); xl[1]=bf2f((unsigned short)(_x>>16));
      xl[2]=bf2f((unsigned short)(_y&0xffffu)); xl[3]=bf2f((unsigned short)(_y>>16));
      xl[4]=bf2f((unsigned short)(_z&0xffffu)); xl[5]=bf2f((unsigned short)(_z>>16));
      xl[6]=bf2f((unsigned short)(_w&0xffffu)); xl[7]=bf2f((unsigned short)(_w>>16)); }
    float bb[8]={b0.x,b0.y,b0.z,b0.w,b1.x,b1.y,b1.z,b1.w};
    float r[8];
    #pragma unroll
    for(int i=0;i<8;i++){
      r[i]=0.5f*(dv*acc[i]+bb[i])+0.5f*xl[i];
      if(RELU) r[i]=fmaxf(r[i],0.f);
    }
    int4 o;
    o.x=(int)pack2(r[0],r[1]); o.y=(int)pack2(r[2],r[3]);
    o.z=(int)pack2(r[4],r[5]); o.w=(int)pack2(r[6],r[7]);
    ((int4*)H)[(size_t)node*16+li]=o;
  }
}

// MLP head: relu(H2@Wm1+bm1)@Wm2+bm2 -> injection -> log_softmax -> out
__launch_bounds__(256)
__global__ void k_mlp(const unsigned short* __restrict__ H2,
                      const unsigned short* __restrict__ Wm1t,
                      const unsigned short* __restrict__ Wm2tp,
                      const float* __restrict__ bm1, const float* __restrict__ bm2,
                      const unsigned char* __restrict__ flag, const float* __restrict__ preds,
                      float* __restrict__ out, int N){
  __shared__ __align__(16) unsigned short zt[4][16][136];
  __shared__ __align__(16) float lt[4][16][16];
  int wave=threadIdx.x>>6, lane=threadIdx.x&63;
  int l15=lane&15, l4=lane>>4;
  int node0=blockIdx.x*64+wave*16;
  int arow=node0+l15; if(arow>N-1) arow=N-1; if(arow<0) arow=0;
  short8 a[4];
  #pragma unroll
  for(int ks=0;ks<4;ks++)
    a[ks]=*reinterpret_cast<const short8*>(H2+(size_t)arow*128+ks*32+l4*8);
  f32x4 acc[8];
  #pragma unroll
  for(int ct=0;ct<8;ct++) acc[ct]=(f32x4){0.f,0.f,0.f,0.f};
  #pragma unroll
  for(int ct=0;ct<8;ct++){
    #pragma unroll
    for(int ks=0;ks<4;ks++){
      short8 bfr=*reinterpret_cast<const short8*>(Wm1t+(size_t)(ct*16+l15)*128+ks*32+l4*8);
      acc[ct]=__builtin_amdgcn_mfma_f32_16x16x32_bf16(bfr,a[ks],acc[ct],0,0,0);
    }
  }
  #pragma unroll
  for(int ct=0;ct<8;ct++){
    float4 bm=*reinterpret_cast<const float4*>(bm1+ct*16+l4*4);
    uint2 p;
    p.x=pack2(fmaxf(acc[ct][0]+bm.x,0.f),fmaxf(acc[ct][1]+bm.y,0.f));
    p.y=pack2(fmaxf(acc[ct][2]+bm.z,0.f),fmaxf(acc[ct][3]+bm.w,0.f));
    *reinterpret_cast<uint2*>(&zt[wave][l15][ct*16+l4*4])=p;
  }
  __syncthreads();
  short8 a2[4];
  #pragma unroll
  for(int ks=0;ks<4;ks++)
    a2[ks]=*reinterpret_cast<const short8*>(&zt[wave][l15][ks*32+l4*8]);
  f32x4 acc2=(f32x4){0.f,0.f,0.f,0.f};
  #pragma unroll
  for(int ks=0;ks<4;ks++){
    short8 bfr=*reinterpret_cast<const short8*>(Wm2tp+(size_t)l15*128+ks*32+l4*8);
    acc2=__builtin_amdgcn_mfma_f32_16x16x32_bf16(bfr,a2[ks],acc2,0,0,0);
  }
  *reinterpret_cast<f32x4*>(&lt[wave][l15][l4*4])=acc2;
  __syncthreads();
  if(lane<16){
    int node=node0+lane;
    if(node<N){
      float v[10];
      #pragma unroll
      for(int c=0;c<10;c++) v[c]=lt[wave][lane][c]+bm2[c];
      if(flag[node]){
        #pragma unroll
        for(int c=0;c<10;c++) v[c]+=INJ_LAM*preds[(size_t)node*10+c];
      }
      float m=v[0];
      #pragma unroll
      for(int c=1;c<10;c++) m=fmaxf(m,v[c]);
      float s=0.f;
      #pragma unroll
      for(int c=0;c<10;c++) s+=expf(v[c]-m);
      float lse=m+logf(s);
      #pragma unroll
      for(int c=0;c<10;c++) out[(size_t)node*10+c]=v[c]-lse;
    }
  }
}

extern "C" void kernel_launch(void* const* d_in, const int* in_sizes, int n_in,
                              void* d_out, int out_size, void* d_ws, size_t ws_size,
                              hipStream_t stream){
  const float* x    =(const float*)d_in[0];
  const int*   ei   =(const int*)  d_in[1];
  const int*   inj  =(const int*)  d_in[2];
  const float* preds=(const float*)d_in[3];
  const float* W1 =(const float*)d_in[4];  const float* b1 =(const float*)d_in[5];
  const float* W2 =(const float*)d_in[6];  const float* b2 =(const float*)d_in[7];
  const float* Wl1=(const float*)d_in[8];  const float* Wl2=(const float*)d_in[9];
  const float* Wm1=(const float*)d_in[10]; const float* bm1=(const float*)d_in[11];
  const float* Wm2=(const float*)d_in[12]; const float* bm2=(const float*)d_in[13];
  float* out=(float*)d_out;

  const int N  = in_sizes[0]/128;
  const int E  = in_sizes[1]/2;
  const int NI = in_sizes[2];
  const int* srcp = ei;
  const int* dstp = ei+E;
  const int NBK = (N+BWD-1)>>BSH;   // buckets (<=256 for N<=131072)

  char* w=(char*)d_ws;
  auto carve=[&](size_t sz)->char*{ char* p=w; w+=(sz+255)&~(size_t)255; return p; };
  unsigned short* S0 =(unsigned short*)carve((size_t)N*128*2); // hb -> h2b
  unsigned short* S1 =(unsigned short*)carve((size_t)N*128*2); // (psrc,pdst) -> g1b -> g2b
  unsigned short* S2 =(unsigned short*)carve((size_t)N*128*2); // rank -> xl1b -> xl2b
  unsigned short* Wt1=(unsigned short*)carve(256*128*2);
  unsigned short* Wt2=(unsigned short*)carve(256*128*2);
  unsigned short* Wm1t=(unsigned short*)carve(128*128*2);
  unsigned short* Wm2tp=(unsigned short*)carve(16*128*2);
  unsigned* cnt   =(unsigned*)carve((size_t)N*4);
  float*    dinv  =(float*)   carve((size_t)N*4);
  unsigned* offs  =(unsigned*)carve((size_t)N*4);
  int*      csr   =(int*)     carve((size_t)E*4);
  unsigned char* flags=(unsigned char*)carve(((size_t)N+3)&~(size_t)3);
  unsigned* bhist8=(unsigned*)carve(256*8*4);
  unsigned* bcur8 =(unsigned*)carve(256*8*4);
  unsigned* bbase =(unsigned*)carve(257*4);
  (void)ws_size; (void)n_in; (void)out_size;

  // overlays (live only before the GEMM chain starts)
  int* psrc=(int*)S1;
  int* pdst=psrc+E;
  unsigned* rank=(unsigned*)S2;

  const int T=256;
  const int EB=(E+2047)/2048;
  hipMemsetAsync(bhist8, 0, 256*8*4, stream);
  hipMemsetAsync(flags, 0, (size_t)N, stream);
  hipLaunchKernelGGL(k_bhist, dim3(EB), dim3(T), 0, stream, dstp, bhist8, inj, flags, E, NI);
  hipLaunchKernelGGL(k_bscan, dim3(1), dim3(T), 0, stream, bhist8, bbase, bcur8, NBK);
  hipLaunchKernelGGL(k_bscatter, dim3(EB), dim3(T), 0, stream, srcp, dstp, bcur8, psrc, pdst, E);
  hipLaunchKernelGGL(k_bucket, dim3(NBK), dim3(T), 0, stream, psrc, pdst, bbase, rank,
                     cnt, offs, dinv, csr, N);
  hipLaunchKernelGGL(k_prepw, dim3(128), dim3(T), 0, stream, W1,Wl1,W2,Wl2,Wm1,Wm2, Wt1,Wt2,Wm1t,Wm2tp);

  dim3 gemmGrid((N+127)/128);
  hipLaunchKernelGGL(k_gemm<true>,  gemmGrid, dim3(T), 0, stream, (const void*)x,  Wt1, dinv, S1, S2, N);
  hipLaunchKernelGGL(k_conv<true>,  dim3((N+3)/4), dim3(T), 0, stream, S1, S2, b1, dinv, csr, offs, cnt, S0, N);
  hipLaunchKernelGGL(k_gemm<false>, gemmGrid, dim3(T), 0, stream, (const void*)S0, Wt2, dinv, S1, S2, N);
  hipLaunchKernelGGL(k_conv<false>, dim3((N+3)/4), dim3(T), 0, stream, S1, S2, b2, dinv, csr, offs, cnt, S0, N);
  hipLaunchKernelGGL(k_mlp, dim3((N+63)/64), dim3(T), 0, stream, S0, Wm1t, Wm2tp, bm1, bm2, flags, preds, out, N);
}

// Round 6
// 346.669 us; speedup vs baseline: 2.0975x; 1.0208x over previous
//
#include <hip/hip_runtime.h>
#include <hip/hip_bf16.h>
#include <math.h>

typedef __attribute__((ext_vector_type(8))) short short8;
typedef __attribute__((ext_vector_type(4))) float f32x4;
typedef __attribute__((ext_vector_type(2))) float f32x2;

#define INJ_LAM 0.8f
#define BSH 9
#define BWD 512   // nodes per bucket

__device__ inline float bf2f(unsigned short s){
  union{unsigned u; float f;} v; v.u=((unsigned)s)<<16; return v.f;
}
__device__ inline unsigned short f2bf(float f){
  __hip_bfloat16 h=__float2bfloat16(f);
  return *reinterpret_cast<unsigned short*>(&h);
}
__device__ inline unsigned pack2(float lo, float hi){
  return ((unsigned)f2bf(hi)<<16)|(unsigned)f2bf(lo);
}

// ---- bucketed CSR build (no per-edge global atomics) ----
__global__ void k_bhist(const int* __restrict__ dst, unsigned* __restrict__ bhist8,
                        const int* __restrict__ inj, unsigned char* __restrict__ flag,
                        int E, int NI){
  __shared__ unsigned lh[256];
  int t=threadIdx.x;
  lh[t]=0u;
  int i=blockIdx.x*256+t;
  if(i<NI) flag[inj[i]]=1;
  __syncthreads();
  int base=blockIdx.x*2048;
  #pragma unroll
  for(int k=0;k<8;k++){
    int e=base+k*256+t;
    if(e<E) atomicAdd(&lh[dst[e]>>BSH],1u);
  }
  __syncthreads();
  if(lh[t]) atomicAdd(&bhist8[t*8],lh[t]);
}

__global__ void k_bscan(const unsigned* __restrict__ bhist8, unsigned* __restrict__ bbase,
                        unsigned* __restrict__ bcur8, int NBK){
  __shared__ unsigned ss[256];
  int t=threadIdx.x;
  unsigned v=(t<NBK)?bhist8[t*8]:0u;
  ss[t]=v; __syncthreads();
  for(int off=1;off<256;off<<=1){
    unsigned u=(t>=off)?ss[t-off]:0u; __syncthreads();
    ss[t]+=u; __syncthreads();
  }
  unsigned excl=ss[t]-v;
  if(t<NBK){ bbase[t]=excl; bcur8[t*8]=excl; }
  if(t==255) bbase[NBK]=ss[255];
}

__global__ void k_bscatter(const int* __restrict__ src, const int* __restrict__ dst,
                           unsigned* __restrict__ bcur8,
                           int* __restrict__ psrc, int* __restrict__ pdst, int E){
  __shared__ unsigned lh[256];
  __shared__ unsigned gb[256];
  int t=threadIdx.x;
  lh[t]=0u; __syncthreads();
  int base=blockIdx.x*2048;
  unsigned lr[8]; int bk[8], sv[8], dv_[8];
  #pragma unroll
  for(int k=0;k<8;k++){
    int e=base+k*256+t;
    if(e<E){
      int d=dst[e]; int b=d>>BSH;
      bk[k]=b; dv_[k]=d; sv[k]=src[e];
      lr[k]=atomicAdd(&lh[b],1u);
    } else bk[k]=-1;
  }
  __syncthreads();
  if(lh[t]) gb[t]=atomicAdd(&bcur8[t*8],lh[t]);
  __syncthreads();
  #pragma unroll
  for(int k=0;k<8;k++){
    if(bk[k]>=0){
      unsigned p=gb[bk[k]]+lr[k];
      psrc[p]=sv[k]; pdst[p]=dv_[k];
    }
  }
}

// bucket: exact per-node cnt+rank via LDS atomics, LDS scan -> offs.
// meta[node] = csr_start | (deg<<21)   (E<2^21, deg<2^11)
__launch_bounds__(256)
__global__ void k_bucket(const int* __restrict__ psrc, const int* __restrict__ pdst,
                         const unsigned* __restrict__ bbase, unsigned* __restrict__ rank,
                         unsigned* __restrict__ meta,
                         float* __restrict__ dinv, int* __restrict__ csr, int N){
  __shared__ unsigned lc[BWD];
  __shared__ unsigned lo[BWD];
  __shared__ unsigned ss[256];
  int b=blockIdx.x, t=threadIdx.x;
  unsigned e0=bbase[b], e1=bbase[b+1];
  int lo_node=b<<BSH;
  lc[t]=0u; lc[t+256]=0u; __syncthreads();
  for(unsigned p=e0+t;p<e1;p+=256){
    int dl=pdst[p]-lo_node;
    rank[p]=atomicAdd(&lc[dl],1u);
  }
  __syncthreads();
  unsigned c0=lc[2*t], c1=lc[2*t+1], ps=c0+c1;
  ss[t]=ps; __syncthreads();
  for(int off=1;off<256;off<<=1){
    unsigned u=(t>=off)?ss[t-off]:0u; __syncthreads();
    ss[t]+=u; __syncthreads();
  }
  unsigned excl=ss[t]-ps;
  lo[2*t]=excl; lo[2*t+1]=excl+c0;
  __syncthreads();
  #pragma unroll
  for(int k=0;k<2;k++){
    int nl=t+k*256; int node=lo_node+nl;
    if(node<N){
      unsigned c=lc[nl];
      meta[node]=(e0+lo[nl])|(c<<21);
      dinv[node]=rsqrtf((float)(c+1u));
    }
  }
  for(unsigned p=e0+t;p<e1;p+=256){
    int dl=pdst[p]-lo_node;
    csr[e0+lo[dl]+rank[p]]=psrc[p];
  }
}

// weights: transpose+cast to bf16 [out][K]; also pre-halved biases
__global__ void k_prepw(const float* __restrict__ W1,const float* __restrict__ Wl1,
                        const float* __restrict__ W2,const float* __restrict__ Wl2,
                        const float* __restrict__ Wm1,const float* __restrict__ Wm2,
                        const float* __restrict__ b1,const float* __restrict__ b2,
                        unsigned short* __restrict__ Wt1, unsigned short* __restrict__ Wt2,
                        unsigned short* __restrict__ Wm1t, unsigned short* __restrict__ Wm2tp,
                        float* __restrict__ bh1, float* __restrict__ bh2){
  int i=blockIdx.x*blockDim.x+threadIdx.x;
  if(i<256*128){
    int c=i>>7, k=i&127;
    float v1=(c<128)?W1[k*128+c]:Wl1[k*128+(c-128)];
    float v2=(c<128)?W2[k*128+c]:Wl2[k*128+(c-128)];
    Wt1[i]=f2bf(v1); Wt2[i]=f2bf(v2);
    if(c<128) Wm1t[i]=f2bf(Wm1[k*128+c]);
    if(c<16)  Wm2tp[i]=f2bf((c<10)?Wm2[k*10+c]:0.f);
    if(i<128){ bh1[i]=0.5f*b1[i]; bh2[i]=0.5f*b2[i]; }
  }
}

template<bool FP32IN>
__device__ inline void load_afrag(const void* __restrict__ Xv, size_t arow, int l4, short8* a){
  if(FP32IN){
    const float* X=(const float*)Xv + arow*128 + l4*8;
    #pragma unroll
    for(int ks=0;ks<4;ks++){
      float4 f0=*reinterpret_cast<const float4*>(X+ks*32);
      float4 f1=*reinterpret_cast<const float4*>(X+ks*32+4);
      short8 t;
      t[0]=(short)f2bf(f0.x); t[1]=(short)f2bf(f0.y); t[2]=(short)f2bf(f0.z); t[3]=(short)f2bf(f0.w);
      t[4]=(short)f2bf(f1.x); t[5]=(short)f2bf(f1.y); t[6]=(short)f2bf(f1.z); t[7]=(short)f2bf(f1.w);
      a[ks]=t;
    }
  }else{
    const unsigned short* X=(const unsigned short*)Xv + arow*128 + l4*8;
    #pragma unroll
    for(int ks=0;ks<4;ks++)
      a[ks]=*reinterpret_cast<const short8*>(X+ks*32);
  }
}

// GEMM: weights in registers (loaded once/block); node tiles stream, 2-stage pipeline.
// XL stored PRE-HALVED (0.5*val) — conv epilogue adds it directly.
template<bool FP32IN>
__launch_bounds__(256, 4)
__global__ void k_gemm(const void* __restrict__ Xv, const unsigned short* __restrict__ Wt,
                       const float* __restrict__ dinv,
                       unsigned short* __restrict__ G, unsigned short* __restrict__ XL, int N){
  int wave=threadIdx.x>>6, lane=threadIdx.x&63;
  int l15=lane&15, l4=lane>>4;
  int blk0=blockIdx.x*128;
  if(blk0>=N) return;
  short8 wf[4][4];
  #pragma unroll
  for(int i=0;i<4;i++){
    int col=(wave*4+i)*16+l15;
    #pragma unroll
    for(int ks=0;ks<4;ks++)
      wf[i][ks]=*reinterpret_cast<const short8*>(Wt+(size_t)col*128+ks*32+l4*8);
  }
  int r0=blk0+l15; if(r0>N-1) r0=N-1;
  short8 aC[4], aN[4];
  load_afrag<FP32IN>(Xv,(size_t)r0,l4,aC);
  #pragma unroll 1
  for(int nt=0;nt<8;nt++){
    int node0=blk0+nt*16;
    if(node0>=N) break;
    if(nt<7){
      int rn=node0+16+l15; if(rn>N-1) rn=N-1;
      load_afrag<FP32IN>(Xv,(size_t)rn,l4,aN);
    }
    f32x4 acc[4];
    #pragma unroll
    for(int i=0;i<4;i++) acc[i]=(f32x4){0.f,0.f,0.f,0.f};
    #pragma unroll
    for(int i=0;i<4;i++){
      #pragma unroll
      for(int ks=0;ks<4;ks++)
        acc[i]=__builtin_amdgcn_mfma_f32_16x16x32_bf16(wf[i][ks],aC[ks],acc[i],0,0,0);
    }
    int node=node0+l15;
    if(node<N){
      if(wave<2){
        float dv=dinv[node];
        #pragma unroll
        for(int i=0;i<4;i++){
          f32x4 v=acc[i];
          uint2 p; p.x=pack2(v[0]*dv,v[1]*dv); p.y=pack2(v[2]*dv,v[3]*dv);
          *reinterpret_cast<uint2*>(G+(size_t)node*128+(wave*4+i)*16+l4*4)=p;
        }
      }else{
        #pragma unroll
        for(int i=0;i<4;i++){
          f32x4 v=acc[i];
          uint2 p; p.x=pack2(v[0]*0.5f,v[1]*0.5f); p.y=pack2(v[2]*0.5f,v[3]*0.5f);
          *reinterpret_cast<uint2*>(XL+(size_t)node*128+((wave-2)*4+i)*16+l4*4)=p;
        }
      }
    }
    #pragma unroll
    for(int ks=0;ks<4;ks++) aC[ks]=aN[ks];
  }
}

// packed f32x2 accumulate (v_pk_add_f32): 3 VALU per u32 instead of 4
#define ADDQ(v) do{ \
  unsigned ux=(unsigned)(v).x, uy=(unsigned)(v).y, uz=(unsigned)(v).z, uw=(unsigned)(v).w; \
  accv[0]+=(f32x2){__uint_as_float(ux<<16),__uint_as_float(ux&0xffff0000u)}; \
  accv[1]+=(f32x2){__uint_as_float(uy<<16),__uint_as_float(uy&0xffff0000u)}; \
  accv[2]+=(f32x2){__uint_as_float(uz<<16),__uint_as_float(uz&0xffff0000u)}; \
  accv[3]+=(f32x2){__uint_as_float(uw<<16),__uint_as_float(uw&0xffff0000u)}; \
}while(0)

// conv: one node per wave; 16 rows in flight (quad per 16-lane group).
// out = dv2*sum + bh + xlh   (bh=0.5*bias, xlh pre-halved, dv2=0.5*dinv)
template<bool RELU>
__launch_bounds__(256)
__global__ void k_conv(const unsigned short* __restrict__ G, const unsigned short* __restrict__ XL,
                       const float* __restrict__ bh, const float* __restrict__ dinv,
                       const int* __restrict__ csr, const unsigned* __restrict__ meta,
                       unsigned short* __restrict__ H, int N){
  int node=blockIdx.x*4+(threadIdx.x>>6);
  if(node>=N) return;
  int lane=threadIdx.x&63;
  int g=lane>>4, li=lane&15;
  const int4* Gv=(const int4*)G;
  const int4 Z={0,0,0,0};
  f32x2 accv[4];
  #pragma unroll
  for(int i=0;i<4;i++) accv[i]=(f32x2){0.f,0.f};
  if(g==0){
    int4 v=Gv[(size_t)node*16+li];       // self-loop term
    ADDQ(v);
  }
  unsigned mt=meta[node];
  unsigned start=mt&0x1FFFFFu, deg=mt>>21;
  unsigned j=(unsigned)g;
  int4 v0=Z,v1=Z,v2=Z,v3=Z;
  if(j<deg)    v0=Gv[(size_t)csr[start+j]*16+li];
  if(j+4<deg)  v1=Gv[(size_t)csr[start+j+4]*16+li];
  if(j+8<deg)  v2=Gv[(size_t)csr[start+j+8]*16+li];
  if(j+12<deg) v3=Gv[(size_t)csr[start+j+12]*16+li];
  j+=16;
  while(j<deg){
    int4 n0=Z,n1=Z,n2=Z,n3=Z;
    n0=Gv[(size_t)csr[start+j]*16+li];
    if(j+4<deg)  n1=Gv[(size_t)csr[start+j+4]*16+li];
    if(j+8<deg)  n2=Gv[(size_t)csr[start+j+8]*16+li];
    if(j+12<deg) n3=Gv[(size_t)csr[start+j+12]*16+li];
    ADDQ(v0); ADDQ(v1); ADDQ(v2); ADDQ(v3);
    v0=n0; v1=n1; v2=n2; v3=n3; j+=16;
  }
  ADDQ(v0); ADDQ(v1); ADDQ(v2); ADDQ(v3);
  float acc[8];
  #pragma unroll
  for(int i=0;i<4;i++){ acc[2*i]=accv[i][0]; acc[2*i+1]=accv[i][1]; }
  #pragma unroll
  for(int i=0;i<8;i++){
    acc[i]+=__shfl_xor(acc[i],16,64);
    acc[i]+=__shfl_xor(acc[i],32,64);
  }
  if(g==0){
    float dv2=0.5f*dinv[node];
    float4 b0=*reinterpret_cast<const float4*>(bh+li*8);
    float4 b1=*reinterpret_cast<const float4*>(bh+li*8+4);
    int4 xv=((const int4*)XL)[(size_t)node*16+li];
    float xl[8];
    { unsigned _x=(unsigned)xv.x,_y=(unsigned)xv.y,_z=(unsigned)xv.z,_w=(unsigned)xv.w;
      xl[0]=bf2f((unsigned short)(_x&0xffffu)); xl[1]=bf2f((unsigned short)(_x>>16));
      xl[2]=bf2f((unsigned short)(_y&0xffffu)); xl[3]=bf2f((unsigned short)(_y>>16));
      xl[4]=bf2f((unsigned short)(_z&0xffffu)); xl[5]=bf2f((unsigned short)(_z>>16));
      xl[6]=bf2f((unsigned short)(_w&0xffffu)); xl[7]=bf2f((unsigned short)(_w>>16)); }
    float bb[8]={b0.x,b0.y,b0.z,b0.w,b1.x,b1.y,b1.z,b1.w};
    float r[8];
    #pragma unroll
    for(int i=0;i<8;i++){
      r[i]=dv2*acc[i]+bb[i]+xl[i];
      if(RELU) r[i]=fmaxf(r[i],0.f);
    }
    int4 o;
    o.x=(int)pack2(r[0],r[1]); o.y=(int)pack2(r[2],r[3]);
    o.z=(int)pack2(r[4],r[5]); o.w=(int)pack2(r[6],r[7]);
    ((int4*)H)[(size_t)node*16+li]=o;
  }
}

// MLP head: relu(H2@Wm1+bm1)@Wm2+bm2 -> injection -> log_softmax -> out
// Epilogue fully wave-parallel: lane(l4,l15) owns classes l4*4..+3 of node l15.
__launch_bounds__(256)
__global__ void k_mlp(const unsigned short* __restrict__ H2,
                      const unsigned short* __restrict__ Wm1t,
                      const unsigned short* __restrict__ Wm2tp,
                      const float* __restrict__ bm1, const float* __restrict__ bm2,
                      const unsigned char* __restrict__ flag, const float* __restrict__ preds,
                      float* __restrict__ out, int N){
  __shared__ __align__(16) unsigned short zt[4][16][136];
  int wave=threadIdx.x>>6, lane=threadIdx.x&63;
  int l15=lane&15, l4=lane>>4;
  int node0=blockIdx.x*64+wave*16;
  int arow=node0+l15; if(arow>N-1) arow=N-1; if(arow<0) arow=0;
  short8 a[4];
  #pragma unroll
  for(int ks=0;ks<4;ks++)
    a[ks]=*reinterpret_cast<const short8*>(H2+(size_t)arow*128+ks*32+l4*8);
  f32x4 acc[8];
  #pragma unroll
  for(int ct=0;ct<8;ct++) acc[ct]=(f32x4){0.f,0.f,0.f,0.f};
  #pragma unroll
  for(int ct=0;ct<8;ct++){
    #pragma unroll
    for(int ks=0;ks<4;ks++){
      short8 bfr=*reinterpret_cast<const short8*>(Wm1t+(size_t)(ct*16+l15)*128+ks*32+l4*8);
      acc[ct]=__builtin_amdgcn_mfma_f32_16x16x32_bf16(bfr,a[ks],acc[ct],0,0,0);
    }
  }
  #pragma unroll
  for(int ct=0;ct<8;ct++){
    float4 bm=*reinterpret_cast<const float4*>(bm1+ct*16+l4*4);
    uint2 p;
    p.x=pack2(fmaxf(acc[ct][0]+bm.x,0.f),fmaxf(acc[ct][1]+bm.y,0.f));
    p.y=pack2(fmaxf(acc[ct][2]+bm.z,0.f),fmaxf(acc[ct][3]+bm.w,0.f));
    *reinterpret_cast<uint2*>(&zt[wave][l15][ct*16+l4*4])=p;
  }
  __syncthreads();
  short8 a2[4];
  #pragma unroll
  for(int ks=0;ks<4;ks++)
    a2[ks]=*reinterpret_cast<const short8*>(&zt[wave][l15][ks*32+l4*8]);
  f32x4 acc2=(f32x4){0.f,0.f,0.f,0.f};
  #pragma unroll
  for(int ks=0;ks<4;ks++){
    short8 bfr=*reinterpret_cast<const short8*>(Wm2tp+(size_t)l15*128+ks*32+l4*8);
    acc2=__builtin_amdgcn_mfma_f32_16x16x32_bf16(bfr,a2[ks],acc2,0,0,0);
  }
  // lane holds node=node0+l15, classes c0=l4*4 .. c0+3
  int node=node0+l15;
  bool have=node<N;
  int c0=l4*4;
  float v[4];
  #pragma unroll
  for(int k=0;k<4;k++){
    int c=c0+k;
    v[k]=(c<10)?(acc2[k]+bm2[c]):-3.0e38f;
  }
  if(have && c0<10 && flag[node]){
    #pragma unroll
    for(int k=0;k<4;k++){
      int c=c0+k;
      if(c<10) v[k]+=INJ_LAM*preds[(size_t)node*10+c];
    }
  }
  float m=fmaxf(fmaxf(v[0],v[1]),fmaxf(v[2],v[3]));
  m=fmaxf(m,__shfl_xor(m,16,64));
  m=fmaxf(m,__shfl_xor(m,32,64));
  float s=0.f;
  #pragma unroll
  for(int k=0;k<4;k++){ int c=c0+k; if(c<10) s+=expf(v[k]-m); }
  s+=__shfl_xor(s,16,64);
  s+=__shfl_xor(s,32,64);
  float lse=m+logf(s);
  if(have && c0<10){
    float2 o01; o01.x=v[0]-lse; o01.y=v[1]-lse;
    *reinterpret_cast<float2*>(out+(size_t)node*10+c0)=o01;
    if(c0+2<10){
      float2 o23; o23.x=v[2]-lse; o23.y=v[3]-lse;
      *reinterpret_cast<float2*>(out+(size_t)node*10+c0+2)=o23;
    }
  }
}

extern "C" void kernel_launch(void* const* d_in, const int* in_sizes, int n_in,
                              void* d_out, int out_size, void* d_ws, size_t ws_size,
                              hipStream_t stream){
  const float* x    =(const float*)d_in[0];
  const int*   ei   =(const int*)  d_in[1];
  const int*   inj  =(const int*)  d_in[2];
  const float* preds=(const float*)d_in[3];
  const float* W1 =(const float*)d_in[4];  const float* b1 =(const float*)d_in[5];
  const float* W2 =(const float*)d_in[6];  const float* b2 =(const float*)d_in[7];
  const float* Wl1=(const float*)d_in[8];  const float* Wl2=(const float*)d_in[9];
  const float* Wm1=(const float*)d_in[10]; const float* bm1=(const float*)d_in[11];
  const float* Wm2=(const float*)d_in[12]; const float* bm2=(const float*)d_in[13];
  float* out=(float*)d_out;

  const int N  = in_sizes[0]/128;
  const int E  = in_sizes[1]/2;
  const int NI = in_sizes[2];
  const int* srcp = ei;
  const int* dstp = ei+E;
  const int NBK = (N+BWD-1)>>BSH;

  char* w=(char*)d_ws;
  auto carve=[&](size_t sz)->char*{ char* p=w; w+=(sz+255)&~(size_t)255; return p; };
  unsigned short* S0 =(unsigned short*)carve((size_t)N*128*2); // hb -> h2b
  unsigned short* S1 =(unsigned short*)carve((size_t)N*128*2); // (psrc,pdst) -> g1b -> g2b
  unsigned short* S2 =(unsigned short*)carve((size_t)N*128*2); // rank -> xl1b -> xl2b
  unsigned short* Wt1=(unsigned short*)carve(256*128*2);
  unsigned short* Wt2=(unsigned short*)carve(256*128*2);
  unsigned short* Wm1t=(unsigned short*)carve(128*128*2);
  unsigned short* Wm2tp=(unsigned short*)carve(16*128*2);
  float*    dinv  =(float*)   carve((size_t)N*4);
  unsigned* meta  =(unsigned*)carve((size_t)N*4);
  int*      csr   =(int*)     carve((size_t)E*4);
  unsigned char* flags=(unsigned char*)carve(((size_t)N+3)&~(size_t)3);
  unsigned* bhist8=(unsigned*)carve(256*8*4);
  unsigned* bcur8 =(unsigned*)carve(256*8*4);
  unsigned* bbase =(unsigned*)carve(257*4);
  float* bh1=(float*)carve(128*4);
  float* bh2=(float*)carve(128*4);
  (void)ws_size; (void)n_in; (void)out_size;

  // overlays (live only before the GEMM chain starts)
  int* psrc=(int*)S1;
  int* pdst=psrc+E;
  unsigned* rank=(unsigned*)S2;

  const int T=256;
  const int EB=(E+2047)/2048;
  hipMemsetAsync(bhist8, 0, 256*8*4, stream);
  hipMemsetAsync(flags, 0, (size_t)N, stream);
  hipLaunchKernelGGL(k_bhist, dim3(EB), dim3(T), 0, stream, dstp, bhist8, inj, flags, E, NI);
  hipLaunchKernelGGL(k_bscan, dim3(1), dim3(T), 0, stream, bhist8, bbase, bcur8, NBK);
  hipLaunchKernelGGL(k_bscatter, dim3(EB), dim3(T), 0, stream, srcp, dstp, bcur8, psrc, pdst, E);
  hipLaunchKernelGGL(k_bucket, dim3(NBK), dim3(T), 0, stream, psrc, pdst, bbase, rank,
                     meta, dinv, csr, N);
  hipLaunchKernelGGL(k_prepw, dim3(128), dim3(T), 0, stream, W1,Wl1,W2,Wl2,Wm1,Wm2,b1,b2,
                     Wt1,Wt2,Wm1t,Wm2tp,bh1,bh2);

  dim3 gemmGrid((N+127)/128);
  hipLaunchKernelGGL(k_gemm<true>,  gemmGrid, dim3(T), 0, stream, (const void*)x,  Wt1, dinv, S1, S2, N);
  hipLaunchKernelGGL(k_conv<true>,  dim3((N+3)/4), dim3(T), 0, stream, S1, S2, bh1, dinv, csr, meta, S0, N);
  hipLaunchKernelGGL(k_gemm<false>, gemmGrid, dim3(T), 0, stream, (const void*)S0, Wt2, dinv, S1, S2, N);
  hipLaunchKernelGGL(k_conv<false>, dim3((N+3)/4), dim3(T), 0, stream, S1, S2, bh2, dinv, csr, meta, S0, N);
  hipLaunchKernelGGL(k_mlp, dim3((N+63)/64), dim3(T), 0, stream, S0, Wm1t, Wm2tp, bm1, bm2, flags, preds, out, N);
}

// Round 7
// 332.094 us; speedup vs baseline: 2.1895x; 1.0439x over previous
//
#include <hip/hip_runtime.h>
#include <hip/hip_bf16.h>
#include <math.h>

typedef __attribute__((ext_vector_type(8))) short short8;
typedef __attribute__((ext_vector_type(4))) float f32x4;
typedef __attribute__((ext_vector_type(2))) float f32x2;

#define INJ_LAM 0.8f
#define BSH 9
#define BWD 512   // nodes per bucket

__device__ inline float bf2f(unsigned short s){
  union{unsigned u; float f;} v; v.u=((unsigned)s)<<16; return v.f;
}
__device__ inline unsigned short f2bf(float f){
  __hip_bfloat16 h=__float2bfloat16(f);
  return *reinterpret_cast<unsigned short*>(&h);
}
__device__ inline unsigned pack2(float lo, float hi){
  return ((unsigned)f2bf(hi)<<16)|(unsigned)f2bf(lo);
}

// prep: weight transpose/cast + pre-halved biases + zero flags/bhist8/zcur
__global__ void k_prep(const float* __restrict__ W1,const float* __restrict__ Wl1,
                       const float* __restrict__ W2,const float* __restrict__ Wl2,
                       const float* __restrict__ Wm1,const float* __restrict__ Wm2,
                       const float* __restrict__ b1,const float* __restrict__ b2,
                       unsigned short* __restrict__ Wt1, unsigned short* __restrict__ Wt2,
                       unsigned short* __restrict__ Wm1t, unsigned short* __restrict__ Wm2tp,
                       float* __restrict__ bh1, float* __restrict__ bh2,
                       unsigned* __restrict__ flags32, int nf4,
                       unsigned* __restrict__ bhist8, unsigned* __restrict__ zcur8){
  int i=blockIdx.x*blockDim.x+threadIdx.x;
  if(i<256*128){
    int c=i>>7, k=i&127;
    float v1=(c<128)?W1[k*128+c]:Wl1[k*128+(c-128)];
    float v2=(c<128)?W2[k*128+c]:Wl2[k*128+(c-128)];
    Wt1[i]=f2bf(v1); Wt2[i]=f2bf(v2);
    if(c<128) Wm1t[i]=f2bf(Wm1[k*128+c]);
    if(c<16)  Wm2tp[i]=f2bf((c<10)?Wm2[k*10+c]:0.f);
    if(i<128){ bh1[i]=0.5f*b1[i]; bh2[i]=0.5f*b2[i]; }
  }
  if(i<nf4) flags32[i]=0u;
  if(i<2048){ bhist8[i]=0u; zcur8[i]=0u; }
}

// bhist: per-block LDS hist of dst>>BSH, padded-sector global merge
__global__ void k_bhist(const int* __restrict__ dst, unsigned* __restrict__ bhist8, int E){
  __shared__ unsigned lh[256];
  int t=threadIdx.x;
  lh[t]=0u; __syncthreads();
  int base=blockIdx.x*2048;
  #pragma unroll
  for(int k=0;k<8;k++){
    int e=base+k*256+t;
    if(e<E) atomicAdd(&lh[dst[e]>>BSH],1u);
  }
  __syncthreads();
  if(lh[t]) atomicAdd(&bhist8[t*8],lh[t]);
}

// bscatter: group edges by bucket; bases re-derived in-block (scan of bhist8),
// inter-block reservation via zeroed zcur8 counters.
__launch_bounds__(256)
__global__ void k_bscatter(const int* __restrict__ src, const int* __restrict__ dst,
                           const unsigned* __restrict__ bhist8, unsigned* __restrict__ zcur8,
                           int* __restrict__ psrc, int* __restrict__ pdst, int E, int NBK){
  __shared__ unsigned lh[256];
  __shared__ unsigned gb[256];
  __shared__ unsigned ss[256];
  int t=threadIdx.x;
  lh[t]=0u;
  unsigned v=(t<NBK)?bhist8[t*8]:0u;
  ss[t]=v; __syncthreads();
  for(int off=1;off<256;off<<=1){
    unsigned u=(t>=off)?ss[t-off]:0u; __syncthreads();
    ss[t]+=u; __syncthreads();
  }
  unsigned bb=ss[t]-v;          // exclusive base of bucket t
  int base=blockIdx.x*2048;
  unsigned lr[8]; int bk[8], sv[8], dv_[8];
  #pragma unroll
  for(int k=0;k<8;k++){
    int e=base+k*256+t;
    if(e<E){
      int d=dst[e]; int b=d>>BSH;
      bk[k]=b; dv_[k]=d; sv[k]=src[e];
      lr[k]=atomicAdd(&lh[b],1u);
    } else bk[k]=-1;
  }
  __syncthreads();
  if(lh[t]) gb[t]=bb+atomicAdd(&zcur8[t*8],lh[t]);
  __syncthreads();
  #pragma unroll
  for(int k=0;k<8;k++){
    if(bk[k]>=0){
      unsigned p=gb[bk[k]]+lr[k];
      psrc[p]=sv[k]; pdst[p]=dv_[k];
    }
  }
}

// bucket: exact per-node cnt+rank via LDS atomics, LDS scan -> offs, write csr.
// meta[node] = csr_start | (deg<<21). Also marks inject flags.
__launch_bounds__(256)
__global__ void k_bucket(const int* __restrict__ psrc, const int* __restrict__ pdst,
                         const unsigned* __restrict__ bhist8, unsigned* __restrict__ rank,
                         unsigned* __restrict__ meta, float* __restrict__ dinv,
                         int* __restrict__ csr,
                         const int* __restrict__ inj, unsigned char* __restrict__ flag,
                         int N, int NI, int NBK){
  __shared__ unsigned lc[BWD];
  __shared__ unsigned lo[BWD];
  __shared__ unsigned ss[256];
  int b=blockIdx.x, t=threadIdx.x;
  for(int i=b*256+t;i<NI;i+=gridDim.x*256) flag[inj[i]]=1;
  unsigned v=(t<NBK)?bhist8[t*8]:0u;
  ss[t]=v; lc[t]=0u; lc[t+256]=0u;
  __syncthreads();
  for(int off=1;off<256;off<<=1){
    unsigned u=(t>=off)?ss[t-off]:0u; __syncthreads();
    ss[t]+=u; __syncthreads();
  }
  unsigned e1=ss[b];
  unsigned e0=e1-bhist8[b*8];
  __syncthreads();
  int lo_node=b<<BSH;
  for(unsigned p=e0+t;p<e1;p+=256){
    int dl=pdst[p]-lo_node;
    rank[p]=atomicAdd(&lc[dl],1u);
  }
  __syncthreads();
  unsigned c0=lc[2*t], c1=lc[2*t+1], ps=c0+c1;
  ss[t]=ps; __syncthreads();
  for(int off=1;off<256;off<<=1){
    unsigned u=(t>=off)?ss[t-off]:0u; __syncthreads();
    ss[t]+=u; __syncthreads();
  }
  unsigned excl=ss[t]-ps;
  lo[2*t]=excl; lo[2*t+1]=excl+c0;
  __syncthreads();
  #pragma unroll
  for(int k=0;k<2;k++){
    int nl=t+k*256; int node=lo_node+nl;
    if(node<N){
      unsigned c=lc[nl];
      meta[node]=(e0+lo[nl])|(c<<21);
      dinv[node]=rsqrtf((float)(c+1u));
    }
  }
  for(unsigned p=e0+t;p<e1;p+=256){
    int dl=pdst[p]-lo_node;
    csr[e0+lo[dl]+rank[p]]=psrc[p];
  }
}

template<bool FP32IN>
__device__ inline void load_afrag(const void* __restrict__ Xv, size_t arow, int l4, short8* a){
  if(FP32IN){
    const float* X=(const float*)Xv + arow*128 + l4*8;
    #pragma unroll
    for(int ks=0;ks<4;ks++){
      float4 f0=*reinterpret_cast<const float4*>(X+ks*32);
      float4 f1=*reinterpret_cast<const float4*>(X+ks*32+4);
      short8 t;
      t[0]=(short)f2bf(f0.x); t[1]=(short)f2bf(f0.y); t[2]=(short)f2bf(f0.z); t[3]=(short)f2bf(f0.w);
      t[4]=(short)f2bf(f1.x); t[5]=(short)f2bf(f1.y); t[6]=(short)f2bf(f1.z); t[7]=(short)f2bf(f1.w);
      a[ks]=t;
    }
  }else{
    const unsigned short* X=(const unsigned short*)Xv + arow*128 + l4*8;
    #pragma unroll
    for(int ks=0;ks<4;ks++)
      a[ks]=*reinterpret_cast<const short8*>(X+ks*32);
  }
}

// GEMM1: weights in registers (loaded once/block); node tiles stream, 2-stage pipeline.
// G = bf16(val*dinv), XL = bf16(0.5*val)
template<bool FP32IN>
__launch_bounds__(256, 4)
__global__ void k_gemm(const void* __restrict__ Xv, const unsigned short* __restrict__ Wt,
                       const float* __restrict__ dinv,
                       unsigned short* __restrict__ G, unsigned short* __restrict__ XL, int N){
  int wave=threadIdx.x>>6, lane=threadIdx.x&63;
  int l15=lane&15, l4=lane>>4;
  int blk0=blockIdx.x*128;
  if(blk0>=N) return;
  short8 wf[4][4];
  #pragma unroll
  for(int i=0;i<4;i++){
    int col=(wave*4+i)*16+l15;
    #pragma unroll
    for(int ks=0;ks<4;ks++)
      wf[i][ks]=*reinterpret_cast<const short8*>(Wt+(size_t)col*128+ks*32+l4*8);
  }
  int r0=blk0+l15; if(r0>N-1) r0=N-1;
  short8 aC[4], aN[4];
  load_afrag<FP32IN>(Xv,(size_t)r0,l4,aC);
  #pragma unroll 1
  for(int nt=0;nt<8;nt++){
    int node0=blk0+nt*16;
    if(node0>=N) break;
    if(nt<7){
      int rn=node0+16+l15; if(rn>N-1) rn=N-1;
      load_afrag<FP32IN>(Xv,(size_t)rn,l4,aN);
    }
    f32x4 acc[4];
    #pragma unroll
    for(int i=0;i<4;i++) acc[i]=(f32x4){0.f,0.f,0.f,0.f};
    #pragma unroll
    for(int i=0;i<4;i++){
      #pragma unroll
      for(int ks=0;ks<4;ks++)
        acc[i]=__builtin_amdgcn_mfma_f32_16x16x32_bf16(wf[i][ks],aC[ks],acc[i],0,0,0);
    }
    int node=node0+l15;
    if(node<N){
      if(wave<2){
        float dv=dinv[node];
        #pragma unroll
        for(int i=0;i<4;i++){
          f32x4 v=acc[i];
          uint2 p; p.x=pack2(v[0]*dv,v[1]*dv); p.y=pack2(v[2]*dv,v[3]*dv);
          *reinterpret_cast<uint2*>(G+(size_t)node*128+(wave*4+i)*16+l4*4)=p;
        }
      }else{
        #pragma unroll
        for(int i=0;i<4;i++){
          f32x4 v=acc[i];
          uint2 p; p.x=pack2(v[0]*0.5f,v[1]*0.5f); p.y=pack2(v[2]*0.5f,v[3]*0.5f);
          *reinterpret_cast<uint2*>(XL+(size_t)node*128+((wave-2)*4+i)*16+l4*4)=p;
        }
      }
    }
    #pragma unroll
    for(int ks=0;ks<4;ks++) aC[ks]=aN[ks];
  }
}

// packed f32x2 accumulate: 3 VALU per u32
#define ADDQ(v) do{ \
  unsigned ux=(unsigned)(v).x, uy=(unsigned)(v).y, uz=(unsigned)(v).z, uw=(unsigned)(v).w; \
  accv[0]+=(f32x2){__uint_as_float(ux<<16),__uint_as_float(ux&0xffff0000u)}; \
  accv[1]+=(f32x2){__uint_as_float(uy<<16),__uint_as_float(uy&0xffff0000u)}; \
  accv[2]+=(f32x2){__uint_as_float(uz<<16),__uint_as_float(uz&0xffff0000u)}; \
  accv[3]+=(f32x2){__uint_as_float(uw<<16),__uint_as_float(uw&0xffff0000u)}; \
}while(0)

// conv for ONE node per wave; result row written as bf16 to LDS (136-elem row).
// out = dv2*sum + bh + xlh   (bh pre-halved, XL pre-halved)
template<bool RELU>
__device__ __forceinline__ void conv_node(int node, int N,
    const unsigned short* __restrict__ G, const unsigned short* __restrict__ XL,
    const float* __restrict__ bh, const float* __restrict__ dinv,
    const int* __restrict__ csr, const unsigned* __restrict__ meta,
    unsigned short* __restrict__ ldsrow, int lane){
  if(node>=N) return;
  int g=lane>>4, li=lane&15;
  const int4* Gv=(const int4*)G;
  const int4 Z={0,0,0,0};
  f32x2 accv[4];
  #pragma unroll
  for(int i=0;i<4;i++) accv[i]=(f32x2){0.f,0.f};
  if(g==0){
    int4 v=Gv[(size_t)node*16+li];       // self-loop term
    ADDQ(v);
  }
  unsigned mt=meta[node];
  unsigned start=mt&0x1FFFFFu, deg=mt>>21;
  unsigned j=(unsigned)g;
  int4 v0=Z,v1=Z,v2=Z,v3=Z;
  if(j<deg)    v0=Gv[(size_t)csr[start+j]*16+li];
  if(j+4<deg)  v1=Gv[(size_t)csr[start+j+4]*16+li];
  if(j+8<deg)  v2=Gv[(size_t)csr[start+j+8]*16+li];
  if(j+12<deg) v3=Gv[(size_t)csr[start+j+12]*16+li];
  j+=16;
  while(j<deg){
    int4 n0=Z,n1=Z,n2=Z,n3=Z;
    n0=Gv[(size_t)csr[start+j]*16+li];
    if(j+4<deg)  n1=Gv[(size_t)csr[start+j+4]*16+li];
    if(j+8<deg)  n2=Gv[(size_t)csr[start+j+8]*16+li];
    if(j+12<deg) n3=Gv[(size_t)csr[start+j+12]*16+li];
    ADDQ(v0); ADDQ(v1); ADDQ(v2); ADDQ(v3);
    v0=n0; v1=n1; v2=n2; v3=n3; j+=16;
  }
  ADDQ(v0); ADDQ(v1); ADDQ(v2); ADDQ(v3);
  float acc[8];
  #pragma unroll
  for(int i=0;i<4;i++){ acc[2*i]=accv[i][0]; acc[2*i+1]=accv[i][1]; }
  #pragma unroll
  for(int i=0;i<8;i++){
    acc[i]+=__shfl_xor(acc[i],16,64);
    acc[i]+=__shfl_xor(acc[i],32,64);
  }
  if(g==0){
    float dv2=0.5f*dinv[node];
    float4 b0=*reinterpret_cast<const float4*>(bh+li*8);
    float4 b1=*reinterpret_cast<const float4*>(bh+li*8+4);
    int4 xv=((const int4*)XL)[(size_t)node*16+li];
    float xl[8];
    { unsigned _x=(unsigned)xv.x,_y=(unsigned)xv.y,_z=(unsigned)xv.z,_w=(unsigned)xv.w;
      xl[0]=bf2f((unsigned short)(_x&0xffffu)); xl[1]=bf2f((unsigned short)(_x>>16));
      xl[2]=bf2f((unsigned short)(_y&0xffffu)); xl[3]=bf2f((unsigned short)(_y>>16));
      xl[4]=bf2f((unsigned short)(_z&0xffffu)); xl[5]=bf2f((unsigned short)(_z>>16));
      xl[6]=bf2f((unsigned short)(_w&0xffffu)); xl[7]=bf2f((unsigned short)(_w>>16)); }
    float bb[8]={b0.x,b0.y,b0.z,b0.w,b1.x,b1.y,b1.z,b1.w};
    float r[8];
    #pragma unroll
    for(int i=0;i<8;i++){
      r[i]=dv2*acc[i]+bb[i]+xl[i];
      if(RELU) r[i]=fmaxf(r[i],0.f);
    }
    int4 o;
    o.x=(int)pack2(r[0],r[1]); o.y=(int)pack2(r[2],r[3]);
    o.z=(int)pack2(r[4],r[5]); o.w=(int)pack2(r[6],r[7]);
    *reinterpret_cast<int4*>(ldsrow+li*8)=o;
  }
}

// fused conv1 + gemm2: block = 8 waves / 32 nodes.
// Phase1: each wave convs 4 nodes -> H-tile in LDS.
// Phase2: 16 col-tiles of Wt2 over 2 node-tiles; G2 overlays XL1 (own rows only).
__launch_bounds__(512, 4)
__global__ void k_convg(const unsigned short* __restrict__ G1, const unsigned short* __restrict__ XL1,
                        const float* __restrict__ bh1, const float* __restrict__ dinv,
                        const int* __restrict__ csr, const unsigned* __restrict__ meta,
                        const unsigned short* __restrict__ Wt2,
                        unsigned short* __restrict__ G2, unsigned short* __restrict__ XL2, int N){
  __shared__ __align__(16) unsigned short ht[32][136];
  int wave=threadIdx.x>>6, lane=threadIdx.x&63;
  int l15=lane&15, l4=lane>>4;
  int blk0=blockIdx.x*32;
  #pragma unroll 1
  for(int it=0;it<4;it++){
    int nl=it*8+wave;
    conv_node<true>(blk0+nl, N, G1, XL1, bh1, dinv, csr, meta, &ht[nl][0], lane);
  }
  short8 wf[2][4];
  #pragma unroll
  for(int i=0;i<2;i++){
    int col=(wave+i*8)*16+l15;
    #pragma unroll
    for(int ks=0;ks<4;ks++)
      wf[i][ks]=*reinterpret_cast<const short8*>(Wt2+(size_t)col*128+ks*32+l4*8);
  }
  __syncthreads();
  #pragma unroll
  for(int q=0;q<2;q++){
    short8 a[4];
    #pragma unroll
    for(int ks=0;ks<4;ks++)
      a[ks]=*reinterpret_cast<const short8*>(&ht[q*16+l15][ks*32+l4*8]);
    int node=blk0+q*16+l15;
    float dv=(node<N)?dinv[node]:0.f;
    #pragma unroll
    for(int i=0;i<2;i++){
      f32x4 acc=(f32x4){0.f,0.f,0.f,0.f};
      #pragma unroll
      for(int ks=0;ks<4;ks++)
        acc=__builtin_amdgcn_mfma_f32_16x16x32_bf16(wf[i][ks],a[ks],acc,0,0,0);
      if(node<N){
        int ct=wave+i*8;
        if(ct<8){
          uint2 p; p.x=pack2(acc[0]*dv,acc[1]*dv); p.y=pack2(acc[2]*dv,acc[3]*dv);
          *reinterpret_cast<uint2*>(G2+(size_t)node*128+ct*16+l4*4)=p;
        }else{
          uint2 p; p.x=pack2(acc[0]*0.5f,acc[1]*0.5f); p.y=pack2(acc[2]*0.5f,acc[3]*0.5f);
          *reinterpret_cast<uint2*>(XL2+(size_t)node*128+(ct-8)*16+l4*4)=p;
        }
      }
    }
  }
}

// fused conv2 + MLP head: block = 8 waves / 32 nodes.
// Phase1: conv2 -> H2-tile LDS. Phase2: Wm1 (8 ct, one per wave) -> zt.
// Phase3: waves 0-1: Wm2 MFMA + injection + log_softmax.
__launch_bounds__(512, 4)
__global__ void k_convm(const unsigned short* __restrict__ G2, const unsigned short* __restrict__ XL2,
                        const float* __restrict__ bh2, const float* __restrict__ dinv,
                        const int* __restrict__ csr, const unsigned* __restrict__ meta,
                        const unsigned short* __restrict__ Wm1t, const unsigned short* __restrict__ Wm2tp,
                        const float* __restrict__ bm1, const float* __restrict__ bm2,
                        const unsigned char* __restrict__ flag, const float* __restrict__ preds,
                        float* __restrict__ out, int N){
  __shared__ __align__(16) unsigned short ht[32][136];
  __shared__ __align__(16) unsigned short zt[32][136];
  int wave=threadIdx.x>>6, lane=threadIdx.x&63;
  int l15=lane&15, l4=lane>>4;
  int blk0=blockIdx.x*32;
  #pragma unroll 1
  for(int it=0;it<4;it++){
    int nl=it*8+wave;
    conv_node<false>(blk0+nl, N, G2, XL2, bh2, dinv, csr, meta, &ht[nl][0], lane);
  }
  short8 wf1[4];
  {
    int col=wave*16+l15;
    #pragma unroll
    for(int ks=0;ks<4;ks++)
      wf1[ks]=*reinterpret_cast<const short8*>(Wm1t+(size_t)col*128+ks*32+l4*8);
  }
  __syncthreads();
  #pragma unroll
  for(int q=0;q<2;q++){
    short8 a[4];
    #pragma unroll
    for(int ks=0;ks<4;ks++)
      a[ks]=*reinterpret_cast<const short8*>(&ht[q*16+l15][ks*32+l4*8]);
    f32x4 acc=(f32x4){0.f,0.f,0.f,0.f};
    #pragma unroll
    for(int ks=0;ks<4;ks++)
      acc=__builtin_amdgcn_mfma_f32_16x16x32_bf16(wf1[ks],a[ks],acc,0,0,0);
    float4 bm=*reinterpret_cast<const float4*>(bm1+wave*16+l4*4);
    uint2 p;
    p.x=pack2(fmaxf(acc[0]+bm.x,0.f),fmaxf(acc[1]+bm.y,0.f));
    p.y=pack2(fmaxf(acc[2]+bm.z,0.f),fmaxf(acc[3]+bm.w,0.f));
    *reinterpret_cast<uint2*>(&zt[q*16+l15][wave*16+l4*4])=p;
  }
  __syncthreads();
  if(wave<2){
    int q=wave;
    short8 a2[4], w2[4];
    #pragma unroll
    for(int ks=0;ks<4;ks++){
      a2[ks]=*reinterpret_cast<const short8*>(&zt[q*16+l15][ks*32+l4*8]);
      w2[ks]=*reinterpret_cast<const short8*>(Wm2tp+(size_t)l15*128+ks*32+l4*8);
    }
    f32x4 acc2=(f32x4){0.f,0.f,0.f,0.f};
    #pragma unroll
    for(int ks=0;ks<4;ks++)
      acc2=__builtin_amdgcn_mfma_f32_16x16x32_bf16(w2[ks],a2[ks],acc2,0,0,0);
    int node=blk0+q*16+l15;
    bool have=node<N;
    int c0=l4*4;
    float v[4];
    #pragma unroll
    for(int k=0;k<4;k++){
      int c=c0+k;
      v[k]=(c<10)?(acc2[k]+bm2[c]):-3.0e38f;
    }
    if(have && c0<10 && flag[node]){
      #pragma unroll
      for(int k=0;k<4;k++){
        int c=c0+k;
        if(c<10) v[k]+=INJ_LAM*preds[(size_t)node*10+c];
      }
    }
    float m=fmaxf(fmaxf(v[0],v[1]),fmaxf(v[2],v[3]));
    m=fmaxf(m,__shfl_xor(m,16,64));
    m=fmaxf(m,__shfl_xor(m,32,64));
    float s=0.f;
    #pragma unroll
    for(int k=0;k<4;k++){ int c=c0+k; if(c<10) s+=expf(v[k]-m); }
    s+=__shfl_xor(s,16,64);
    s+=__shfl_xor(s,32,64);
    float lse=m+logf(s);
    if(have && c0<10){
      float2 o01; o01.x=v[0]-lse; o01.y=v[1]-lse;
      *reinterpret_cast<float2*>(out+(size_t)node*10+c0)=o01;
      if(c0+2<10){
        float2 o23; o23.x=v[2]-lse; o23.y=v[3]-lse;
        *reinterpret_cast<float2*>(out+(size_t)node*10+c0+2)=o23;
      }
    }
  }
}

extern "C" void kernel_launch(void* const* d_in, const int* in_sizes, int n_in,
                              void* d_out, int out_size, void* d_ws, size_t ws_size,
                              hipStream_t stream){
  const float* x    =(const float*)d_in[0];
  const int*   ei   =(const int*)  d_in[1];
  const int*   inj  =(const int*)  d_in[2];
  const float* preds=(const float*)d_in[3];
  const float* W1 =(const float*)d_in[4];  const float* b1 =(const float*)d_in[5];
  const float* W2 =(const float*)d_in[6];  const float* b2 =(const float*)d_in[7];
  const float* Wl1=(const float*)d_in[8];  const float* Wl2=(const float*)d_in[9];
  const float* Wm1=(const float*)d_in[10]; const float* bm1=(const float*)d_in[11];
  const float* Wm2=(const float*)d_in[12]; const float* bm2=(const float*)d_in[13];
  float* out=(float*)d_out;

  const int N  = in_sizes[0]/128;
  const int E  = in_sizes[1]/2;
  const int NI = in_sizes[2];
  const int* srcp = ei;
  const int* dstp = ei+E;
  const int NBK = (N+BWD-1)>>BSH;

  char* w=(char*)d_ws;
  auto carve=[&](size_t sz)->char*{ char* p=w; w+=(sz+255)&~(size_t)255; return p; };
  unsigned short* S1 =(unsigned short*)carve((size_t)N*128*2); // G1 (random-read by convg)
  unsigned short* S2 =(unsigned short*)carve((size_t)N*128*2); // XL1 -> G2 (own-row overlay)
  unsigned short* S3 =(unsigned short*)carve((size_t)N*128*2); // XL2; graph overlay psrc/pdst
  unsigned short* Wt1=(unsigned short*)carve(256*128*2);
  unsigned short* Wt2=(unsigned short*)carve(256*128*2);
  unsigned short* Wm1t=(unsigned short*)carve(128*128*2);
  unsigned short* Wm2tp=(unsigned short*)carve(16*128*2);
  float*    dinv  =(float*)   carve((size_t)N*4);
  unsigned* meta  =(unsigned*)carve((size_t)N*4);
  int*      csr   =(int*)     carve((size_t)E*4);
  unsigned char* flags=(unsigned char*)carve(((size_t)N+3)&~(size_t)3);
  unsigned* bhist8=(unsigned*)carve(256*8*4);
  unsigned* zcur8 =(unsigned*)carve(256*8*4);
  float* bh1=(float*)carve(128*4);
  float* bh2=(float*)carve(128*4);
  (void)ws_size; (void)n_in; (void)out_size;

  // graph-phase overlays (dead before gemm1/convg write S1/S3)
  int* psrc=(int*)S3;
  int* pdst=psrc+E;
  unsigned* rank=(unsigned*)S1;

  const int T=256;
  const int EB=(E+2047)/2048;
  const int nf4=(N+3)/4;
  int gp=(32768>nf4?32768:nf4); gp=(gp+T-1)/T;
  hipLaunchKernelGGL(k_prep, dim3(gp), dim3(T), 0, stream,
                     W1,Wl1,W2,Wl2,Wm1,Wm2,b1,b2,
                     Wt1,Wt2,Wm1t,Wm2tp,bh1,bh2,
                     (unsigned*)flags, nf4, bhist8, zcur8);
  hipLaunchKernelGGL(k_bhist, dim3(EB), dim3(T), 0, stream, dstp, bhist8, E);
  hipLaunchKernelGGL(k_bscatter, dim3(EB), dim3(T), 0, stream, srcp, dstp, bhist8, zcur8,
                     psrc, pdst, E, NBK);
  hipLaunchKernelGGL(k_bucket, dim3(NBK), dim3(T), 0, stream, psrc, pdst, bhist8, rank,
                     meta, dinv, csr, inj, flags, N, NI, NBK);
  hipLaunchKernelGGL(k_gemm<true>, dim3((N+127)/128), dim3(T), 0, stream,
                     (const void*)x, Wt1, dinv, S1, S2, N);
  hipLaunchKernelGGL(k_convg, dim3((N+31)/32), dim3(512), 0, stream,
                     S1, S2, bh1, dinv, csr, meta, Wt2, S2, S3, N);
  hipLaunchKernelGGL(k_convm, dim3((N+31)/32), dim3(512), 0, stream,
                     S2, S3, bh2, dinv, csr, meta, Wm1t, Wm2tp, bm1, bm2,
                     flags, preds, out, N);
}

// Round 8
// 327.397 us; speedup vs baseline: 2.2210x; 1.0143x over previous
//
#include <hip/hip_runtime.h>
#include <hip/hip_bf16.h>
#include <math.h>

typedef __attribute__((ext_vector_type(8))) short short8;
typedef __attribute__((ext_vector_type(4))) float f32x4;
typedef __attribute__((ext_vector_type(2))) float f32x2;

#define INJ_LAM 0.8f
#define BSH 9
#define BWD 512   // nodes per bucket

__device__ inline float bf2f(unsigned short s){
  union{unsigned u; float f;} v; v.u=((unsigned)s)<<16; return v.f;
}
__device__ inline unsigned short f2bf(float f){
  __hip_bfloat16 h=__float2bfloat16(f);
  return *reinterpret_cast<unsigned short*>(&h);
}
__device__ inline unsigned pack2(float lo, float hi){
  return ((unsigned)f2bf(hi)<<16)|(unsigned)f2bf(lo);
}

// prep: weight transpose/cast + pre-halved biases + zero flags/bhist8/zcur
__global__ void k_prep(const float* __restrict__ W1,const float* __restrict__ Wl1,
                       const float* __restrict__ W2,const float* __restrict__ Wl2,
                       const float* __restrict__ Wm1,const float* __restrict__ Wm2,
                       const float* __restrict__ b1,const float* __restrict__ b2,
                       unsigned short* __restrict__ Wt1, unsigned short* __restrict__ Wt2,
                       unsigned short* __restrict__ Wm1t, unsigned short* __restrict__ Wm2tp,
                       float* __restrict__ bh1, float* __restrict__ bh2,
                       unsigned* __restrict__ flags32, int nf4,
                       unsigned* __restrict__ bhist8, unsigned* __restrict__ zcur8){
  int i=blockIdx.x*blockDim.x+threadIdx.x;
  if(i<256*128){
    int c=i>>7, k=i&127;
    float v1=(c<128)?W1[k*128+c]:Wl1[k*128+(c-128)];
    float v2=(c<128)?W2[k*128+c]:Wl2[k*128+(c-128)];
    Wt1[i]=f2bf(v1); Wt2[i]=f2bf(v2);
    if(c<128) Wm1t[i]=f2bf(Wm1[k*128+c]);
    if(c<16)  Wm2tp[i]=f2bf((c<10)?Wm2[k*10+c]:0.f);
    if(i<128){ bh1[i]=0.5f*b1[i]; bh2[i]=0.5f*b2[i]; }
  }
  if(i<nf4) flags32[i]=0u;
  if(i<2048){ bhist8[i]=0u; zcur8[i]=0u; }
}

// bhist: per-block LDS hist of dst>>BSH, padded-sector global merge
__global__ void k_bhist(const int* __restrict__ dst, unsigned* __restrict__ bhist8, int E){
  __shared__ unsigned lh[256];
  int t=threadIdx.x;
  lh[t]=0u; __syncthreads();
  int base=blockIdx.x*2048;
  #pragma unroll
  for(int k=0;k<8;k++){
    int e=base+k*256+t;
    if(e<E) atomicAdd(&lh[dst[e]>>BSH],1u);
  }
  __syncthreads();
  if(lh[t]) atomicAdd(&bhist8[t*8],lh[t]);
}

// bscatter: group edges by bucket; bases re-derived in-block (scan of bhist8),
// inter-block reservation via zeroed zcur8 counters.
__launch_bounds__(256)
__global__ void k_bscatter(const int* __restrict__ src, const int* __restrict__ dst,
                           const unsigned* __restrict__ bhist8, unsigned* __restrict__ zcur8,
                           int* __restrict__ psrc, int* __restrict__ pdst, int E, int NBK){
  __shared__ unsigned lh[256];
  __shared__ unsigned gb[256];
  __shared__ unsigned ss[256];
  int t=threadIdx.x;
  lh[t]=0u;
  unsigned v=(t<NBK)?bhist8[t*8]:0u;
  ss[t]=v; __syncthreads();
  for(int off=1;off<256;off<<=1){
    unsigned u=(t>=off)?ss[t-off]:0u; __syncthreads();
    ss[t]+=u; __syncthreads();
  }
  unsigned bb=ss[t]-v;          // exclusive base of bucket t
  int base=blockIdx.x*2048;
  unsigned lr[8]; int bk[8], sv[8], dv_[8];
  #pragma unroll
  for(int k=0;k<8;k++){
    int e=base+k*256+t;
    if(e<E){
      int d=dst[e]; int b=d>>BSH;
      bk[k]=b; dv_[k]=d; sv[k]=src[e];
      lr[k]=atomicAdd(&lh[b],1u);
    } else bk[k]=-1;
  }
  __syncthreads();
  if(lh[t]) gb[t]=bb+atomicAdd(&zcur8[t*8],lh[t]);
  __syncthreads();
  #pragma unroll
  for(int k=0;k<8;k++){
    if(bk[k]>=0){
      unsigned p=gb[bk[k]]+lr[k];
      psrc[p]=sv[k]; pdst[p]=dv_[k];
    }
  }
}

// bucket: exact per-node cnt+rank via LDS atomics, LDS scan -> offs, write csr.
// meta[node] = csr_start | (deg<<21). Also marks inject flags.
__launch_bounds__(256)
__global__ void k_bucket(const int* __restrict__ psrc, const int* __restrict__ pdst,
                         const unsigned* __restrict__ bhist8, unsigned* __restrict__ rank,
                         unsigned* __restrict__ meta, float* __restrict__ dinv,
                         int* __restrict__ csr,
                         const int* __restrict__ inj, unsigned char* __restrict__ flag,
                         int N, int NI, int NBK){
  __shared__ unsigned lc[BWD];
  __shared__ unsigned lo[BWD];
  __shared__ unsigned ss[256];
  int b=blockIdx.x, t=threadIdx.x;
  for(int i=b*256+t;i<NI;i+=gridDim.x*256) flag[inj[i]]=1;
  unsigned v=(t<NBK)?bhist8[t*8]:0u;
  ss[t]=v; lc[t]=0u; lc[t+256]=0u;
  __syncthreads();
  for(int off=1;off<256;off<<=1){
    unsigned u=(t>=off)?ss[t-off]:0u; __syncthreads();
    ss[t]+=u; __syncthreads();
  }
  unsigned e1=ss[b];
  unsigned e0=e1-bhist8[b*8];
  __syncthreads();
  int lo_node=b<<BSH;
  for(unsigned p=e0+t;p<e1;p+=256){
    int dl=pdst[p]-lo_node;
    rank[p]=atomicAdd(&lc[dl],1u);
  }
  __syncthreads();
  unsigned c0=lc[2*t], c1=lc[2*t+1], ps=c0+c1;
  ss[t]=ps; __syncthreads();
  for(int off=1;off<256;off<<=1){
    unsigned u=(t>=off)?ss[t-off]:0u; __syncthreads();
    ss[t]+=u; __syncthreads();
  }
  unsigned excl=ss[t]-ps;
  lo[2*t]=excl; lo[2*t+1]=excl+c0;
  __syncthreads();
  #pragma unroll
  for(int k=0;k<2;k++){
    int nl=t+k*256; int node=lo_node+nl;
    if(node<N){
      unsigned c=lc[nl];
      meta[node]=(e0+lo[nl])|(c<<21);
      dinv[node]=rsqrtf((float)(c+1u));
    }
  }
  for(unsigned p=e0+t;p<e1;p+=256){
    int dl=pdst[p]-lo_node;
    csr[e0+lo[dl]+rank[p]]=psrc[p];
  }
}

template<bool FP32IN>
__device__ inline void load_afrag(const void* __restrict__ Xv, size_t arow, int l4, short8* a){
  if(FP32IN){
    const float* X=(const float*)Xv + arow*128 + l4*8;
    #pragma unroll
    for(int ks=0;ks<4;ks++){
      float4 f0=*reinterpret_cast<const float4*>(X+ks*32);
      float4 f1=*reinterpret_cast<const float4*>(X+ks*32+4);
      short8 t;
      t[0]=(short)f2bf(f0.x); t[1]=(short)f2bf(f0.y); t[2]=(short)f2bf(f0.z); t[3]=(short)f2bf(f0.w);
      t[4]=(short)f2bf(f1.x); t[5]=(short)f2bf(f1.y); t[6]=(short)f2bf(f1.z); t[7]=(short)f2bf(f1.w);
      a[ks]=t;
    }
  }else{
    const unsigned short* X=(const unsigned short*)Xv + arow*128 + l4*8;
    #pragma unroll
    for(int ks=0;ks<4;ks++)
      a[ks]=*reinterpret_cast<const short8*>(X+ks*32);
  }
}

// GEMM1: weights in registers (loaded once/block); node tiles stream, 2-stage pipeline.
// G = bf16(val*dinv), XL = bf16(0.5*val)
template<bool FP32IN>
__launch_bounds__(256, 4)
__global__ void k_gemm(const void* __restrict__ Xv, const unsigned short* __restrict__ Wt,
                       const float* __restrict__ dinv,
                       unsigned short* __restrict__ G, unsigned short* __restrict__ XL, int N){
  int wave=threadIdx.x>>6, lane=threadIdx.x&63;
  int l15=lane&15, l4=lane>>4;
  int blk0=blockIdx.x*128;
  if(blk0>=N) return;
  short8 wf[4][4];
  #pragma unroll
  for(int i=0;i<4;i++){
    int col=(wave*4+i)*16+l15;
    #pragma unroll
    for(int ks=0;ks<4;ks++)
      wf[i][ks]=*reinterpret_cast<const short8*>(Wt+(size_t)col*128+ks*32+l4*8);
  }
  int r0=blk0+l15; if(r0>N-1) r0=N-1;
  short8 aC[4], aN[4];
  load_afrag<FP32IN>(Xv,(size_t)r0,l4,aC);
  #pragma unroll 1
  for(int nt=0;nt<8;nt++){
    int node0=blk0+nt*16;
    if(node0>=N) break;
    if(nt<7){
      int rn=node0+16+l15; if(rn>N-1) rn=N-1;
      load_afrag<FP32IN>(Xv,(size_t)rn,l4,aN);
    }
    f32x4 acc[4];
    #pragma unroll
    for(int i=0;i<4;i++) acc[i]=(f32x4){0.f,0.f,0.f,0.f};
    #pragma unroll
    for(int i=0;i<4;i++){
      #pragma unroll
      for(int ks=0;ks<4;ks++)
        acc[i]=__builtin_amdgcn_mfma_f32_16x16x32_bf16(wf[i][ks],aC[ks],acc[i],0,0,0);
    }
    int node=node0+l15;
    if(node<N){
      if(wave<2){
        float dv=dinv[node];
        #pragma unroll
        for(int i=0;i<4;i++){
          f32x4 v=acc[i];
          uint2 p; p.x=pack2(v[0]*dv,v[1]*dv); p.y=pack2(v[2]*dv,v[3]*dv);
          *reinterpret_cast<uint2*>(G+(size_t)node*128+(wave*4+i)*16+l4*4)=p;
        }
      }else{
        #pragma unroll
        for(int i=0;i<4;i++){
          f32x4 v=acc[i];
          uint2 p; p.x=pack2(v[0]*0.5f,v[1]*0.5f); p.y=pack2(v[2]*0.5f,v[3]*0.5f);
          *reinterpret_cast<uint2*>(XL+(size_t)node*128+((wave-2)*4+i)*16+l4*4)=p;
        }
      }
    }
    #pragma unroll
    for(int ks=0;ks<4;ks++) aC[ks]=aN[ks];
  }
}

// packed f32x2 accumulate: 3 VALU per u32
#define ADDQ(v) do{ \
  unsigned ux=(unsigned)(v).x, uy=(unsigned)(v).y, uz=(unsigned)(v).z, uw=(unsigned)(v).w; \
  accv[0]+=(f32x2){__uint_as_float(ux<<16),__uint_as_float(ux&0xffff0000u)}; \
  accv[1]+=(f32x2){__uint_as_float(uy<<16),__uint_as_float(uy&0xffff0000u)}; \
  accv[2]+=(f32x2){__uint_as_float(uz<<16),__uint_as_float(uz&0xffff0000u)}; \
  accv[3]+=(f32x2){__uint_as_float(uw<<16),__uint_as_float(uw&0xffff0000u)}; \
}while(0)

// conv for ONE node per 16-lane GROUP (no cross-lane reduce needed: each lane
// owns a 16B column chunk). 4-deep row pipeline. Result row -> LDS (bf16).
// out = dv2*sum + bh + xlh   (bh pre-halved, XL pre-halved)
template<bool RELU>
__device__ __forceinline__ void conv_group(int node, int N,
    const unsigned short* __restrict__ G, const unsigned short* __restrict__ XL,
    const float* __restrict__ bh, const float* __restrict__ dinv,
    const int* __restrict__ csr, const unsigned* __restrict__ meta,
    unsigned short* __restrict__ ldsrow, int li){
  if(node>=N) return;
  const int4* Gv=(const int4*)G;
  const int4 Z={0,0,0,0};
  f32x2 accv[4];
  #pragma unroll
  for(int i=0;i<4;i++) accv[i]=(f32x2){0.f,0.f};
  { int4 v=Gv[(size_t)node*16+li]; ADDQ(v); }   // self-loop term
  unsigned mt=meta[node];
  unsigned start=mt&0x1FFFFFu, deg=mt>>21;
  int4 v0=Z,v1=Z,v2=Z,v3=Z;
  if(0u<deg) v0=Gv[(size_t)csr[start  ]*16+li];
  if(1u<deg) v1=Gv[(size_t)csr[start+1]*16+li];
  if(2u<deg) v2=Gv[(size_t)csr[start+2]*16+li];
  if(3u<deg) v3=Gv[(size_t)csr[start+3]*16+li];
  unsigned j=4;
  while(j<deg){
    int4 n0=Gv[(size_t)csr[start+j]*16+li];
    int4 n1=(j+1<deg)?Gv[(size_t)csr[start+j+1]*16+li]:Z;
    int4 n2=(j+2<deg)?Gv[(size_t)csr[start+j+2]*16+li]:Z;
    int4 n3=(j+3<deg)?Gv[(size_t)csr[start+j+3]*16+li]:Z;
    ADDQ(v0); ADDQ(v1); ADDQ(v2); ADDQ(v3);
    v0=n0; v1=n1; v2=n2; v3=n3; j+=4;
  }
  ADDQ(v0); ADDQ(v1); ADDQ(v2); ADDQ(v3);
  float acc[8];
  #pragma unroll
  for(int i=0;i<4;i++){ acc[2*i]=accv[i][0]; acc[2*i+1]=accv[i][1]; }
  float dv2=0.5f*dinv[node];
  float4 b0=*reinterpret_cast<const float4*>(bh+li*8);
  float4 b1=*reinterpret_cast<const float4*>(bh+li*8+4);
  int4 xv=((const int4*)XL)[(size_t)node*16+li];
  float xl[8];
  { unsigned _x=(unsigned)xv.x,_y=(unsigned)xv.y,_z=(unsigned)xv.z,_w=(unsigned)xv.w;
    xl[0]=bf2f((unsigned short)(_x&0xffffu)); xl[1]=bf2f((unsigned short)(_x>>16));
    xl[2]=bf2f((unsigned short)(_y&0xffffu)); xl[3]=bf2f((unsigned short)(_y>>16));
    xl[4]=bf2f((unsigned short)(_z&0xffffu)); xl[5]=bf2f((unsigned short)(_z>>16));
    xl[6]=bf2f((unsigned short)(_w&0xffffu)); xl[7]=bf2f((unsigned short)(_w>>16)); }
  float bb[8]={b0.x,b0.y,b0.z,b0.w,b1.x,b1.y,b1.z,b1.w};
  float r[8];
  #pragma unroll
  for(int i=0;i<8;i++){
    r[i]=dv2*acc[i]+bb[i]+xl[i];
    if(RELU) r[i]=fmaxf(r[i],0.f);
  }
  int4 o;
  o.x=(int)pack2(r[0],r[1]); o.y=(int)pack2(r[2],r[3]);
  o.z=(int)pack2(r[4],r[5]); o.w=(int)pack2(r[6],r[7]);
  *reinterpret_cast<int4*>(ldsrow+li*8)=o;
}

// fused conv1 + gemm2: block = 4 waves / 16 nodes, one node per 16-lane group.
// Phase2: 16 col-tiles of Wt2 (4/wave), weights from L2 post-barrier.
// G2 overlays XL1 (own rows only).
__launch_bounds__(256, 6)
__global__ void k_convg(const unsigned short* __restrict__ G1, const unsigned short* __restrict__ XL1,
                        const float* __restrict__ bh1, const float* __restrict__ dinv,
                        const int* __restrict__ csr, const unsigned* __restrict__ meta,
                        const unsigned short* __restrict__ Wt2,
                        unsigned short* __restrict__ G2, unsigned short* __restrict__ XL2, int N){
  __shared__ __align__(16) unsigned short ht[16][136];
  int wave=threadIdx.x>>6, lane=threadIdx.x&63;
  int l15=lane&15, l4=lane>>4;
  int blk0=blockIdx.x*16;
  int nl=wave*4+l4;                      // group index 0..15 = node slot
  conv_group<true>(blk0+nl, N, G1, XL1, bh1, dinv, csr, meta, &ht[nl][0], l15);
  __syncthreads();
  short8 a[4];
  #pragma unroll
  for(int ks=0;ks<4;ks++)
    a[ks]=*reinterpret_cast<const short8*>(&ht[l15][ks*32+l4*8]);
  int node=blk0+l15;
  float dv=(node<N)?dinv[node]:0.f;
  #pragma unroll
  for(int i=0;i<4;i++){
    int ct=wave*4+i;
    short8 wfr[4];
    #pragma unroll
    for(int ks=0;ks<4;ks++)
      wfr[ks]=*reinterpret_cast<const short8*>(Wt2+(size_t)(ct*16+l15)*128+ks*32+l4*8);
    f32x4 acc=(f32x4){0.f,0.f,0.f,0.f};
    #pragma unroll
    for(int ks=0;ks<4;ks++)
      acc=__builtin_amdgcn_mfma_f32_16x16x32_bf16(wfr[ks],a[ks],acc,0,0,0);
    if(node<N){
      if(ct<8){
        uint2 p; p.x=pack2(acc[0]*dv,acc[1]*dv); p.y=pack2(acc[2]*dv,acc[3]*dv);
        *reinterpret_cast<uint2*>(G2+(size_t)node*128+ct*16+l4*4)=p;
      }else{
        uint2 p; p.x=pack2(acc[0]*0.5f,acc[1]*0.5f); p.y=pack2(acc[2]*0.5f,acc[3]*0.5f);
        *reinterpret_cast<uint2*>(XL2+(size_t)node*128+(ct-8)*16+l4*4)=p;
      }
    }
  }
}

// fused conv2 + MLP head: block = 4 waves / 16 nodes.
// Phase2: Wm1 (8 ct, 2/wave) -> zt. Phase3: wave 0: Wm2 + injection + log_softmax.
__launch_bounds__(256, 6)
__global__ void k_convm(const unsigned short* __restrict__ G2, const unsigned short* __restrict__ XL2,
                        const float* __restrict__ bh2, const float* __restrict__ dinv,
                        const int* __restrict__ csr, const unsigned* __restrict__ meta,
                        const unsigned short* __restrict__ Wm1t, const unsigned short* __restrict__ Wm2tp,
                        const float* __restrict__ bm1, const float* __restrict__ bm2,
                        const unsigned char* __restrict__ flag, const float* __restrict__ preds,
                        float* __restrict__ out, int N){
  __shared__ __align__(16) unsigned short ht[16][136];
  __shared__ __align__(16) unsigned short zt[16][136];
  int wave=threadIdx.x>>6, lane=threadIdx.x&63;
  int l15=lane&15, l4=lane>>4;
  int blk0=blockIdx.x*16;
  int nl=wave*4+l4;
  conv_group<false>(blk0+nl, N, G2, XL2, bh2, dinv, csr, meta, &ht[nl][0], l15);
  __syncthreads();
  short8 a[4];
  #pragma unroll
  for(int ks=0;ks<4;ks++)
    a[ks]=*reinterpret_cast<const short8*>(&ht[l15][ks*32+l4*8]);
  #pragma unroll
  for(int i=0;i<2;i++){
    int ct=wave*2+i;
    short8 wfr[4];
    #pragma unroll
    for(int ks=0;ks<4;ks++)
      wfr[ks]=*reinterpret_cast<const short8*>(Wm1t+(size_t)(ct*16+l15)*128+ks*32+l4*8);
    f32x4 acc=(f32x4){0.f,0.f,0.f,0.f};
    #pragma unroll
    for(int ks=0;ks<4;ks++)
      acc=__builtin_amdgcn_mfma_f32_16x16x32_bf16(wfr[ks],a[ks],acc,0,0,0);
    float4 bm=*reinterpret_cast<const float4*>(bm1+ct*16+l4*4);
    uint2 p;
    p.x=pack2(fmaxf(acc[0]+bm.x,0.f),fmaxf(acc[1]+bm.y,0.f));
    p.y=pack2(fmaxf(acc[2]+bm.z,0.f),fmaxf(acc[3]+bm.w,0.f));
    *reinterpret_cast<uint2*>(&zt[l15][ct*16+l4*4])=p;
  }
  __syncthreads();
  if(wave==0){
    short8 a2[4], w2[4];
    #pragma unroll
    for(int ks=0;ks<4;ks++){
      a2[ks]=*reinterpret_cast<const short8*>(&zt[l15][ks*32+l4*8]);
      w2[ks]=*reinterpret_cast<const short8*>(Wm2tp+(size_t)l15*128+ks*32+l4*8);
    }
    f32x4 acc2=(f32x4){0.f,0.f,0.f,0.f};
    #pragma unroll
    for(int ks=0;ks<4;ks++)
      acc2=__builtin_amdgcn_mfma_f32_16x16x32_bf16(w2[ks],a2[ks],acc2,0,0,0);
    int node=blk0+l15;
    bool have=node<N;
    int c0=l4*4;
    float v[4];
    #pragma unroll
    for(int k=0;k<4;k++){
      int c=c0+k;
      v[k]=(c<10)?(acc2[k]+bm2[c]):-3.0e38f;
    }
    if(have && c0<10 && flag[node]){
      #pragma unroll
      for(int k=0;k<4;k++){
        int c=c0+k;
        if(c<10) v[k]+=INJ_LAM*preds[(size_t)node*10+c];
      }
    }
    float m=fmaxf(fmaxf(v[0],v[1]),fmaxf(v[2],v[3]));
    m=fmaxf(m,__shfl_xor(m,16,64));
    m=fmaxf(m,__shfl_xor(m,32,64));
    float s=0.f;
    #pragma unroll
    for(int k=0;k<4;k++){ int c=c0+k; if(c<10) s+=expf(v[k]-m); }
    s+=__shfl_xor(s,16,64);
    s+=__shfl_xor(s,32,64);
    float lse=m+logf(s);
    if(have && c0<10){
      float2 o01; o01.x=v[0]-lse; o01.y=v[1]-lse;
      *reinterpret_cast<float2*>(out+(size_t)node*10+c0)=o01;
      if(c0+2<10){
        float2 o23; o23.x=v[2]-lse; o23.y=v[3]-lse;
        *reinterpret_cast<float2*>(out+(size_t)node*10+c0+2)=o23;
      }
    }
  }
}

extern "C" void kernel_launch(void* const* d_in, const int* in_sizes, int n_in,
                              void* d_out, int out_size, void* d_ws, size_t ws_size,
                              hipStream_t stream){
  const float* x    =(const float*)d_in[0];
  const int*   ei   =(const int*)  d_in[1];
  const int*   inj  =(const int*)  d_in[2];
  const float* preds=(const float*)d_in[3];
  const float* W1 =(const float*)d_in[4];  const float* b1 =(const float*)d_in[5];
  const float* W2 =(const float*)d_in[6];  const float* b2 =(const float*)d_in[7];
  const float* Wl1=(const float*)d_in[8];  const float* Wl2=(const float*)d_in[9];
  const float* Wm1=(const float*)d_in[10]; const float* bm1=(const float*)d_in[11];
  const float* Wm2=(const float*)d_in[12]; const float* bm2=(const float*)d_in[13];
  float* out=(float*)d_out;

  const int N  = in_sizes[0]/128;
  const int E  = in_sizes[1]/2;
  const int NI = in_sizes[2];
  const int* srcp = ei;
  const int* dstp = ei+E;
  const int NBK = (N+BWD-1)>>BSH;

  char* w=(char*)d_ws;
  auto carve=[&](size_t sz)->char*{ char* p=w; w+=(sz+255)&~(size_t)255; return p; };
  unsigned short* S1 =(unsigned short*)carve((size_t)N*128*2); // G1 (random-read by convg)
  unsigned short* S2 =(unsigned short*)carve((size_t)N*128*2); // XL1 -> G2 (own-row overlay)
  unsigned short* S3 =(unsigned short*)carve((size_t)N*128*2); // XL2; graph overlay psrc/pdst
  unsigned short* Wt1=(unsigned short*)carve(256*128*2);
  unsigned short* Wt2=(unsigned short*)carve(256*128*2);
  unsigned short* Wm1t=(unsigned short*)carve(128*128*2);
  unsigned short* Wm2tp=(unsigned short*)carve(16*128*2);
  float*    dinv  =(float*)   carve((size_t)N*4);
  unsigned* meta  =(unsigned*)carve((size_t)N*4);
  int*      csr   =(int*)     carve((size_t)E*4);
  unsigned char* flags=(unsigned char*)carve(((size_t)N+3)&~(size_t)3);
  unsigned* bhist8=(unsigned*)carve(256*8*4);
  unsigned* zcur8 =(unsigned*)carve(256*8*4);
  float* bh1=(float*)carve(128*4);
  float* bh2=(float*)carve(128*4);
  (void)ws_size; (void)n_in; (void)out_size;

  // graph-phase overlays (dead before gemm1/convg write S1/S3)
  int* psrc=(int*)S3;
  int* pdst=psrc+E;
  unsigned* rank=(unsigned*)S1;

  const int T=256;
  const int EB=(E+2047)/2048;
  const int nf4=(N+3)/4;
  int gp=(32768>nf4?32768:nf4); gp=(gp+T-1)/T;
  hipLaunchKernelGGL(k_prep, dim3(gp), dim3(T), 0, stream,
                     W1,Wl1,W2,Wl2,Wm1,Wm2,b1,b2,
                     Wt1,Wt2,Wm1t,Wm2tp,bh1,bh2,
                     (unsigned*)flags, nf4, bhist8, zcur8);
  hipLaunchKernelGGL(k_bhist, dim3(EB), dim3(T), 0, stream, dstp, bhist8, E);
  hipLaunchKernelGGL(k_bscatter, dim3(EB), dim3(T), 0, stream, srcp, dstp, bhist8, zcur8,
                     psrc, pdst, E, NBK);
  hipLaunchKernelGGL(k_bucket, dim3(NBK), dim3(T), 0, stream, psrc, pdst, bhist8, rank,
                     meta, dinv, csr, inj, flags, N, NI, NBK);
  hipLaunchKernelGGL(k_gemm<true>, dim3((N+127)/128), dim3(T), 0, stream,
                     (const void*)x, Wt1, dinv, S1, S2, N);
  hipLaunchKernelGGL(k_convg, dim3((N+15)/16), dim3(T), 0, stream,
                     S1, S2, bh1, dinv, csr, meta, Wt2, S2, S3, N);
  hipLaunchKernelGGL(k_convm, dim3((N+15)/16), dim3(T), 0, stream,
                     S2, S3, bh2, dinv, csr, meta, Wm1t, Wm2tp, bm1, bm2,
                     flags, preds, out, N);
}